// Round 1
// baseline (1164.607 us; speedup 1.0000x reference)
//
#include <hip/hip_runtime.h>
#include <hip/hip_bf16.h>

#define NB 8
#define NS 1024
#define ND 1024
#define NH 16
#define NDK 64
#define NDFF 4096

typedef __bf16 bf16;
typedef __attribute__((ext_vector_type(8))) __bf16 bf16x8;
typedef __attribute__((ext_vector_type(4))) __bf16 bf16x4;
typedef __attribute__((ext_vector_type(4))) float f32x4;

__device__ __forceinline__ void gload16(const bf16* g, bf16* l) {
  __builtin_amdgcn_global_load_lds(
      (const __attribute__((address_space(1))) void*)g,
      (__attribute__((address_space(3))) void*)l, 16, 0, 0);
}

// ---- weight convert + transpose: W f32 [K][N] -> WT bf16 [N][K] ----
__global__ void wconv_t(const float* __restrict__ W, bf16* __restrict__ WT,
                        int K, int N) {
  __shared__ float tile[32][33];
  int n0 = blockIdx.x * 32, k0 = blockIdx.y * 32;
  int tx = threadIdx.x, ty = threadIdx.y;
#pragma unroll
  for (int i2 = 0; i2 < 4; ++i2) {
    int i = ty + i2 * 8;
    tile[i][tx] = W[(long)(k0 + i) * N + n0 + tx];
  }
  __syncthreads();
#pragma unroll
  for (int i2 = 0; i2 < 4; ++i2) {
    int i = ty + i2 * 8;
    WT[(long)(n0 + i) * K + k0 + tx] = (bf16)tile[tx][i];
  }
}

// ---- fused layernorm: out_ln = bf16(LN(x)), out_lnpos = bf16(LN(x)+pos) ----
__global__ void ln_fused(const float* __restrict__ in, const float* __restrict__ gam,
                         const float* __restrict__ bet, const float* __restrict__ pos,
                         bf16* __restrict__ out_ln, bf16* __restrict__ out_lnpos) {
  long row = blockIdx.x;
  int t = threadIdx.x;  // 256
  float4 v = ((const float4*)(in + row * ND))[t];
  float s = v.x + v.y + v.z + v.w;
  float s2 = v.x * v.x + v.y * v.y + v.z * v.z + v.w * v.w;
#pragma unroll
  for (int m = 32; m >= 1; m >>= 1) {
    s += __shfl_xor(s, m);
    s2 += __shfl_xor(s2, m);
  }
  __shared__ float red[8];
  if ((t & 63) == 0) {
    red[t >> 6] = s;
    red[4 + (t >> 6)] = s2;
  }
  __syncthreads();
  float ts = red[0] + red[1] + red[2] + red[3];
  float ts2 = red[4] + red[5] + red[6] + red[7];
  float mu = ts * (1.0f / ND);
  float var = ts2 * (1.0f / ND) - mu * mu;
  float rstd = rsqrtf(var + 1e-5f);
  float4 g4 = ((const float4*)gam)[t];
  float4 b4 = ((const float4*)bet)[t];
  float o0 = (v.x - mu) * rstd * g4.x + b4.x;
  float o1 = (v.y - mu) * rstd * g4.y + b4.y;
  float o2 = (v.z - mu) * rstd * g4.z + b4.z;
  float o3 = (v.w - mu) * rstd * g4.w + b4.w;
  if (out_ln) {
    bf16x4 q;
    q[0] = (bf16)o0; q[1] = (bf16)o1; q[2] = (bf16)o2; q[3] = (bf16)o3;
    *(bf16x4*)(out_ln + row * ND + t * 4) = q;
  }
  if (out_lnpos) {
    float4 p4 = ((const float4*)(pos + row * ND))[t];
    bf16x4 q;
    q[0] = (bf16)(o0 + p4.x); q[1] = (bf16)(o1 + p4.y);
    q[2] = (bf16)(o2 + p4.z); q[3] = (bf16)(o3 + p4.w);
    *(bf16x4*)(out_lnpos + row * ND + t * 4) = q;
  }
}

// ---- GEMM: C[M,N] = A[M,K] @ WT[N,K]^T + bias ; m97 structure (128x128, BK=32)
// MODE 0: bf16 out.  MODE 1: f32 out = res + v.  MODE 2: bf16 out = swish(v).
template <int MODE>
__global__ __launch_bounds__(256) void gemm_bt(
    const bf16* __restrict__ A, const bf16* __restrict__ WT,
    const float* __restrict__ bias, const float* __restrict__ res,
    void* __restrict__ out, int M, int N, int K) {
  __shared__ bf16 As[128 * 32];
  __shared__ bf16 Bs[128 * 32];
  int t = threadIdx.x;
  int l = t & 63, w = t >> 6;
  int wr = w >> 1, wc = w & 1;
  int c16 = l & 15, g8 = (l >> 4) * 8;
  long row0 = (long)blockIdx.y * 128;
  long col0 = (long)blockIdx.x * 128;

  f32x4 acc[4][4];
#pragma unroll
  for (int m = 0; m < 4; ++m)
#pragma unroll
    for (int n = 0; n < 4; ++n) acc[m][n] = (f32x4){0.f, 0.f, 0.f, 0.f};

  const bf16* Ag = A + (row0 + (t >> 2)) * K + (t & 3) * 8;
  const bf16* Bg = WT + (col0 + (t >> 2)) * K + (t & 3) * 8;

  for (int k0 = 0; k0 < K; k0 += 32) {
    gload16(Ag + k0, &As[w * 512]);
    gload16(Ag + 64 * (long)K + k0, &As[2048 + w * 512]);
    gload16(Bg + k0, &Bs[w * 512]);
    gload16(Bg + 64 * (long)K + k0, &Bs[2048 + w * 512]);
    __syncthreads();
    bf16x8 a[4], b[4];
#pragma unroll
    for (int m = 0; m < 4; ++m)
      a[m] = *(const bf16x8*)&As[(wr * 64 + m * 16 + c16) * 32 + g8];
#pragma unroll
    for (int n = 0; n < 4; ++n)
      b[n] = *(const bf16x8*)&Bs[(wc * 64 + n * 16 + c16) * 32 + g8];
#pragma unroll
    for (int m = 0; m < 4; ++m)
#pragma unroll
      for (int n = 0; n < 4; ++n)
        acc[m][n] = __builtin_amdgcn_mfma_f32_16x16x32_bf16(a[m], b[n], acc[m][n], 0, 0, 0);
    __syncthreads();
  }

#pragma unroll
  for (int n = 0; n < 4; ++n) {
    long col = col0 + wc * 64 + n * 16 + c16;
    float bv = bias[col];
#pragma unroll
    for (int m = 0; m < 4; ++m) {
      long rowb = row0 + wr * 64 + m * 16 + (l >> 4) * 4;
#pragma unroll
      for (int r = 0; r < 4; ++r) {
        float v = acc[m][n][r] + bv;
        long idx = (rowb + r) * N + col;
        if (MODE == 0) {
          ((bf16*)out)[idx] = (bf16)v;
        } else if (MODE == 1) {
          ((float*)out)[idx] = res[idx] + v;
        } else {
          float sw = v / (1.f + __expf(-v));
          ((bf16*)out)[idx] = (bf16)sw;
        }
      }
    }
  }
}

// ---- V transpose per head: V [B*S][D] -> VT [B*H][DK][S] ----
__global__ void vtrans(const bf16* __restrict__ V, bf16* __restrict__ VT) {
  __shared__ bf16 tile[32][33];
  int st = blockIdx.x * 32, dt = blockIdx.y * 32;
  int bh = blockIdx.z;
  int b = bh >> 4, h = bh & 15;
  int tx = threadIdx.x, ty = threadIdx.y;
#pragma unroll
  for (int i2 = 0; i2 < 4; ++i2) {
    int i = ty + i2 * 8;
    tile[i][tx] = V[((long)b * NS + st + i) * ND + h * NDK + dt + tx];
  }
  __syncthreads();
#pragma unroll
  for (int i2 = 0; i2 < 4; ++i2) {
    int i = ty + i2 * 8;
    VT[((long)bh * NDK + dt + i) * NS + st + tx] = tile[tx][i];
  }
}

// ---- flash attention: Q,K [B*S][D] per-head cols; VT [B*H][DK][S]; O bf16 ----
__global__ __launch_bounds__(256) void attn_fwd(
    const bf16* __restrict__ Q, const bf16* __restrict__ Kt,
    const bf16* __restrict__ VT, bf16* __restrict__ O) {
  int w = threadIdx.x >> 6;
  int l = threadIdx.x & 63;
  int qt = blockIdx.x * 4 + w;
  int h = blockIdx.y, b = blockIdx.z;
  int c16 = l & 15, g = l >> 4;
  __shared__ bf16 P_lds[4][16 * 32];

  const bf16* Qb = Q + ((long)(b * NS + qt * 16 + c16)) * ND + h * NDK;
  bf16x8 aq0 = *(const bf16x8*)(Qb + g * 8);
  bf16x8 aq1 = *(const bf16x8*)(Qb + 32 + g * 8);

  const bf16* Kb = Kt + (long)b * NS * ND + h * NDK;
  const bf16* Vb = VT + (long)(b * NH + h) * NDK * NS;

  f32x4 o[4];
#pragma unroll
  for (int n = 0; n < 4; ++n) o[n] = (f32x4){0.f, 0.f, 0.f, 0.f};
  float mx[4] = {-1e30f, -1e30f, -1e30f, -1e30f};
  float ls[4] = {0.f, 0.f, 0.f, 0.f};

  for (int kv = 0; kv < NS; kv += 32) {
    const bf16* K0 = Kb + (long)(kv + c16) * ND;
    const bf16* K1 = Kb + (long)(kv + 16 + c16) * ND;
    bf16x8 b00 = *(const bf16x8*)(K0 + g * 8);
    bf16x8 b01 = *(const bf16x8*)(K0 + 32 + g * 8);
    bf16x8 b10 = *(const bf16x8*)(K1 + g * 8);
    bf16x8 b11 = *(const bf16x8*)(K1 + 32 + g * 8);
    f32x4 s0 = (f32x4){0.f, 0.f, 0.f, 0.f};
    f32x4 s1 = (f32x4){0.f, 0.f, 0.f, 0.f};
    s0 = __builtin_amdgcn_mfma_f32_16x16x32_bf16(aq0, b00, s0, 0, 0, 0);
    s0 = __builtin_amdgcn_mfma_f32_16x16x32_bf16(aq1, b01, s0, 0, 0, 0);
    s1 = __builtin_amdgcn_mfma_f32_16x16x32_bf16(aq0, b10, s1, 0, 0, 0);
    s1 = __builtin_amdgcn_mfma_f32_16x16x32_bf16(aq1, b11, s1, 0, 0, 0);

#pragma unroll
    for (int r = 0; r < 4; ++r) {
      float a0 = s0[r] * 0.125f, a1 = s1[r] * 0.125f;
      float tm = fmaxf(a0, a1);
      tm = fmaxf(tm, __shfl_xor(tm, 1));
      tm = fmaxf(tm, __shfl_xor(tm, 2));
      tm = fmaxf(tm, __shfl_xor(tm, 4));
      tm = fmaxf(tm, __shfl_xor(tm, 8));
      float mn = fmaxf(mx[r], tm);
      float sc = __expf(mx[r] - mn);
      mx[r] = mn;
      float p0 = __expf(a0 - mn), p1 = __expf(a1 - mn);
      float rs = p0 + p1;
      rs += __shfl_xor(rs, 1);
      rs += __shfl_xor(rs, 2);
      rs += __shfl_xor(rs, 4);
      rs += __shfl_xor(rs, 8);
      ls[r] = ls[r] * sc + rs;
      o[0][r] *= sc; o[1][r] *= sc; o[2][r] *= sc; o[3][r] *= sc;
      P_lds[w][(4 * g + r) * 32 + c16] = (bf16)p0;
      P_lds[w][(4 * g + r) * 32 + 16 + c16] = (bf16)p1;
    }
    __syncthreads();
    bf16x8 ap = *(const bf16x8*)&P_lds[w][c16 * 32 + g * 8];
#pragma unroll
    for (int nf = 0; nf < 4; ++nf) {
      bf16x8 bv = *(const bf16x8*)(Vb + (long)(nf * 16 + c16) * NS + kv + g * 8);
      o[nf] = __builtin_amdgcn_mfma_f32_16x16x32_bf16(ap, bv, o[nf], 0, 0, 0);
    }
    __syncthreads();
  }

#pragma unroll
  for (int nf = 0; nf < 4; ++nf) {
#pragma unroll
    for (int r = 0; r < 4; ++r) {
      float v = o[nf][r] / ls[r];
      O[((long)(b * NS + qt * 16 + 4 * g + r)) * ND + h * NDK + nf * 16 + c16] = (bf16)v;
    }
  }
}

extern "C" void kernel_launch(void* const* d_in, const int* in_sizes, int n_in,
                              void* d_out, int out_size, void* d_ws, size_t ws_size,
                              hipStream_t stream) {
  (void)in_sizes; (void)n_in; (void)out_size; (void)ws_size;
  const float* x = (const float*)d_in[0];
  const float* y = (const float*)d_in[1];
  const float* x_pos = (const float*)d_in[2];
  const float* y_pos = (const float*)d_in[3];

  char* ws = (char*)d_ws;
  const size_t MB = 1ull << 20;
  bf16* Wt[8];
  for (int i = 0; i < 8; ++i) Wt[i] = (bf16*)(ws + (size_t)i * 2 * MB);
  bf16* W1T = (bf16*)(ws + 16 * MB);
  bf16* W2T = (bf16*)(ws + 24 * MB);
  float* xres = (float*)(ws + 32 * MB);
  bf16* x2 = (bf16*)(ws + 64 * MB);
  bf16* qk = (bf16*)(ws + 80 * MB);
  bf16* y2 = (bf16*)(ws + 96 * MB);
  bf16* yk = (bf16*)(ws + 112 * MB);
  bf16* Qb = (bf16*)(ws + 128 * MB);
  bf16* Kb = (bf16*)(ws + 144 * MB);
  bf16* Vb = (bf16*)(ws + 160 * MB);
  bf16* VTb = (bf16*)(ws + 176 * MB);
  bf16* Ob = (bf16*)(ws + 192 * MB);
  bf16* hb = (bf16*)(ws + 128 * MB);  // aliases Qb..VTb (free during FFN)

  dim3 tb(32, 8);
  // weights: sa_wq..sa_wo, ca_wq..ca_wo at d_in[4,6,8,10,12,14,16,18]
  for (int i = 0; i < 8; ++i)
    wconv_t<<<dim3(32, 32), tb, 0, stream>>>((const float*)d_in[4 + 2 * i], Wt[i], 1024, 1024);
  wconv_t<<<dim3(128, 32), tb, 0, stream>>>((const float*)d_in[20], W1T, 1024, 4096);
  wconv_t<<<dim3(32, 128), tb, 0, stream>>>((const float*)d_in[22], W2T, 4096, 1024);

  const float* ln1g = (const float*)d_in[24]; const float* ln1b = (const float*)d_in[25];
  const float* ln2g = (const float*)d_in[26]; const float* ln2b = (const float*)d_in[27];
  const float* ln3g = (const float*)d_in[28]; const float* ln3b = (const float*)d_in[29];
  const float* ln4g = (const float*)d_in[30]; const float* ln4b = (const float*)d_in[31];

  dim3 gD(8, 64);     // N=1024 GEMMs
  dim3 gF1(32, 64);   // N=4096
  dim3 gVT(32, 2, 128);
  dim3 gAT(16, 16, 8);

  // ---- self-attention ----
  ln_fused<<<8192, 256, 0, stream>>>(x, ln1g, ln1b, x_pos, x2, qk);
  gemm_bt<0><<<gD, 256, 0, stream>>>(qk, Wt[0], (const float*)d_in[5], nullptr, Qb, 8192, 1024, 1024);
  gemm_bt<0><<<gD, 256, 0, stream>>>(qk, Wt[1], (const float*)d_in[7], nullptr, Kb, 8192, 1024, 1024);
  gemm_bt<0><<<gD, 256, 0, stream>>>(x2, Wt[2], (const float*)d_in[9], nullptr, Vb, 8192, 1024, 1024);
  vtrans<<<gVT, tb, 0, stream>>>(Vb, VTb);
  attn_fwd<<<gAT, 256, 0, stream>>>(Qb, Kb, VTb, Ob);
  gemm_bt<1><<<gD, 256, 0, stream>>>(Ob, Wt[3], (const float*)d_in[11], x, xres, 8192, 1024, 1024);

  // ---- cross-attention ----
  ln_fused<<<8192, 256, 0, stream>>>(xres, ln2g, ln2b, x_pos, nullptr, qk);
  ln_fused<<<8192, 256, 0, stream>>>(y, ln3g, ln3b, y_pos, y2, yk);
  gemm_bt<0><<<gD, 256, 0, stream>>>(qk, Wt[4], (const float*)d_in[13], nullptr, Qb, 8192, 1024, 1024);
  gemm_bt<0><<<gD, 256, 0, stream>>>(yk, Wt[5], (const float*)d_in[15], nullptr, Kb, 8192, 1024, 1024);
  gemm_bt<0><<<gD, 256, 0, stream>>>(y2, Wt[6], (const float*)d_in[17], nullptr, Vb, 8192, 1024, 1024);
  vtrans<<<gVT, tb, 0, stream>>>(Vb, VTb);
  attn_fwd<<<gAT, 256, 0, stream>>>(Qb, Kb, VTb, Ob);
  gemm_bt<1><<<gD, 256, 0, stream>>>(Ob, Wt[7], (const float*)d_in[19], xres, xres, 8192, 1024, 1024);

  // ---- FFN ----
  ln_fused<<<8192, 256, 0, stream>>>(xres, ln4g, ln4b, nullptr, x2, nullptr);
  gemm_bt<2><<<gF1, 256, 0, stream>>>(x2, W1T, (const float*)d_in[21], nullptr, hb, 8192, 4096, 1024);
  gemm_bt<1><<<gD, 256, 0, stream>>>(hb, W2T, (const float*)d_in[23], xres, (float*)d_out, 8192, 1024, 4096);
}

// Round 2
// 1163.727 us; speedup vs baseline: 1.0008x; 1.0008x over previous
//
#include <hip/hip_runtime.h>
#include <hip/hip_bf16.h>

#define NB 8
#define NS 1024
#define ND 1024
#define NH 16
#define NDK 64
#define NDFF 4096

typedef __bf16 bf16;
typedef __attribute__((ext_vector_type(8))) __bf16 bf16x8;
typedef __attribute__((ext_vector_type(4))) __bf16 bf16x4;
typedef __attribute__((ext_vector_type(4))) float f32x4;

__device__ __forceinline__ void gload16(const bf16* g, bf16* l) {
  __builtin_amdgcn_global_load_lds(
      (const __attribute__((address_space(1))) void*)g,
      (__attribute__((address_space(3))) void*)l, 16, 0, 0);
}

// ---- weight convert + transpose: W f32 [K][N] -> WT bf16 [N][K] ----
__global__ void wconv_t(const float* __restrict__ W, bf16* __restrict__ WT,
                        int K, int N) {
  __shared__ float tile[32][33];
  int n0 = blockIdx.x * 32, k0 = blockIdx.y * 32;
  int tx = threadIdx.x, ty = threadIdx.y;
#pragma unroll
  for (int i2 = 0; i2 < 4; ++i2) {
    int i = ty + i2 * 8;
    tile[i][tx] = W[(long)(k0 + i) * N + n0 + tx];
  }
  __syncthreads();
#pragma unroll
  for (int i2 = 0; i2 < 4; ++i2) {
    int i = ty + i2 * 8;
    WT[(long)(n0 + i) * K + k0 + tx] = (bf16)tile[tx][i];
  }
}

// ---- fused layernorm: out_ln = bf16(LN(x)), out_lnpos = bf16(LN(x)+pos) ----
__global__ void ln_fused(const float* __restrict__ in, const float* __restrict__ gam,
                         const float* __restrict__ bet, const float* __restrict__ pos,
                         bf16* __restrict__ out_ln, bf16* __restrict__ out_lnpos) {
  long row = blockIdx.x;
  int t = threadIdx.x;  // 256
  float4 v = ((const float4*)(in + row * ND))[t];
  float s = v.x + v.y + v.z + v.w;
  float s2 = v.x * v.x + v.y * v.y + v.z * v.z + v.w * v.w;
#pragma unroll
  for (int m = 32; m >= 1; m >>= 1) {
    s += __shfl_xor(s, m);
    s2 += __shfl_xor(s2, m);
  }
  __shared__ float red[8];
  if ((t & 63) == 0) {
    red[t >> 6] = s;
    red[4 + (t >> 6)] = s2;
  }
  __syncthreads();
  float ts = red[0] + red[1] + red[2] + red[3];
  float ts2 = red[4] + red[5] + red[6] + red[7];
  float mu = ts * (1.0f / ND);
  float var = ts2 * (1.0f / ND) - mu * mu;
  float rstd = rsqrtf(var + 1e-5f);
  float4 g4 = ((const float4*)gam)[t];
  float4 b4 = ((const float4*)bet)[t];
  float o0 = (v.x - mu) * rstd * g4.x + b4.x;
  float o1 = (v.y - mu) * rstd * g4.y + b4.y;
  float o2 = (v.z - mu) * rstd * g4.z + b4.z;
  float o3 = (v.w - mu) * rstd * g4.w + b4.w;
  if (out_ln) {
    bf16x4 q;
    q[0] = (bf16)o0; q[1] = (bf16)o1; q[2] = (bf16)o2; q[3] = (bf16)o3;
    *(bf16x4*)(out_ln + row * ND + t * 4) = q;
  }
  if (out_lnpos) {
    float4 p4 = ((const float4*)(pos + row * ND))[t];
    bf16x4 q;
    q[0] = (bf16)(o0 + p4.x); q[1] = (bf16)(o1 + p4.y);
    q[2] = (bf16)(o2 + p4.z); q[3] = (bf16)(o3 + p4.w);
    *(bf16x4*)(out_lnpos + row * ND + t * 4) = q;
  }
}

// ---- GEMM: C[M,N] = A[M,K] @ WT[N,K]^T + bias ; m97 structure (128x128, BK=32)
// MODE 0: bf16 out.  MODE 1: f32 out = res + v.  MODE 2: bf16 out = swish(v).
template <int MODE>
__global__ __launch_bounds__(256) void gemm_bt(
    const bf16* __restrict__ A, const bf16* __restrict__ WT,
    const float* __restrict__ bias, const float* __restrict__ res,
    void* __restrict__ out, int M, int N, int K) {
  __shared__ bf16 As[128 * 32];
  __shared__ bf16 Bs[128 * 32];
  int t = threadIdx.x;
  int l = t & 63, w = t >> 6;
  int wr = w >> 1, wc = w & 1;
  int c16 = l & 15, g8 = (l >> 4) * 8;
  long row0 = (long)blockIdx.y * 128;
  long col0 = (long)blockIdx.x * 128;

  f32x4 acc[4][4];
#pragma unroll
  for (int m = 0; m < 4; ++m)
#pragma unroll
    for (int n = 0; n < 4; ++n) acc[m][n] = (f32x4){0.f, 0.f, 0.f, 0.f};

  const bf16* Ag = A + (row0 + (t >> 2)) * K + (t & 3) * 8;
  const bf16* Bg = WT + (col0 + (t >> 2)) * K + (t & 3) * 8;

  for (int k0 = 0; k0 < K; k0 += 32) {
    gload16(Ag + k0, &As[w * 512]);
    gload16(Ag + 64 * (long)K + k0, &As[2048 + w * 512]);
    gload16(Bg + k0, &Bs[w * 512]);
    gload16(Bg + 64 * (long)K + k0, &Bs[2048 + w * 512]);
    __syncthreads();
    bf16x8 a[4], b[4];
#pragma unroll
    for (int m = 0; m < 4; ++m)
      a[m] = *(const bf16x8*)&As[(wr * 64 + m * 16 + c16) * 32 + g8];
#pragma unroll
    for (int n = 0; n < 4; ++n)
      b[n] = *(const bf16x8*)&Bs[(wc * 64 + n * 16 + c16) * 32 + g8];
#pragma unroll
    for (int m = 0; m < 4; ++m)
#pragma unroll
      for (int n = 0; n < 4; ++n)
        acc[m][n] = __builtin_amdgcn_mfma_f32_16x16x32_bf16(a[m], b[n], acc[m][n], 0, 0, 0);
    __syncthreads();
  }

#pragma unroll
  for (int n = 0; n < 4; ++n) {
    long col = col0 + wc * 64 + n * 16 + c16;
    float bv = bias[col];
#pragma unroll
    for (int m = 0; m < 4; ++m) {
      long rowb = row0 + wr * 64 + m * 16 + (l >> 4) * 4;
#pragma unroll
      for (int r = 0; r < 4; ++r) {
        float v = acc[m][n][r] + bv;
        long idx = (rowb + r) * N + col;
        if (MODE == 0) {
          ((bf16*)out)[idx] = (bf16)v;
        } else if (MODE == 1) {
          ((float*)out)[idx] = res[idx] + v;
        } else {
          float sw = v / (1.f + __expf(-v));
          ((bf16*)out)[idx] = (bf16)sw;
        }
      }
    }
  }
}

// ---- V transpose per head: V [B*S][D] -> VT [B*H][DK][S] ----
__global__ void vtrans(const bf16* __restrict__ V, bf16* __restrict__ VT) {
  __shared__ bf16 tile[32][33];
  int st = blockIdx.x * 32, dt = blockIdx.y * 32;
  int bh = blockIdx.z;
  int b = bh >> 4, h = bh & 15;
  int tx = threadIdx.x, ty = threadIdx.y;
#pragma unroll
  for (int i2 = 0; i2 < 4; ++i2) {
    int i = ty + i2 * 8;
    tile[i][tx] = V[((long)b * NS + st + i) * ND + h * NDK + dt + tx];
  }
  __syncthreads();
#pragma unroll
  for (int i2 = 0; i2 < 4; ++i2) {
    int i = ty + i2 * 8;
    VT[((long)bh * NDK + dt + i) * NS + st + tx] = tile[tx][i];
  }
}

// ---- swapped-operand flash attention (m214 structure, DK=64) ----
// Per wave: 16 q-rows, KVBLK=32, no __syncthreads at all.
// S^T = mfma(K_frag, Q_frag): lane owns one q-col's scores -> in-register
// softmax (7 fmax + 2 shfl). P roundtrips per-wave LDS; O^T = mfma(VT, P^T).
__global__ __launch_bounds__(256) void attn_fwd(
    const bf16* __restrict__ Q, const bf16* __restrict__ Kt,
    const bf16* __restrict__ VT, bf16* __restrict__ O) {
  int w = threadIdx.x >> 6;
  int l = threadIdx.x & 63;
  int qt = blockIdx.x * 4 + w;
  int h = blockIdx.y, b = blockIdx.z;
  int c = l & 15, g = l >> 4;
  __shared__ bf16 Pl[4][2][16][40];  // per-wave, double-buffered, padded

  const bf16* Qrow = Q + (long)(b * NS + qt * 16 + c) * ND + h * NDK + g * 8;
  bf16x8 qf0 = *(const bf16x8*)(Qrow);
  bf16x8 qf1 = *(const bf16x8*)(Qrow + 32);

  const bf16* Kb = Kt + (long)b * NS * ND + h * NDK;
  const bf16* Vb = VT + (long)(b * NH + h) * NDK * NS;

  f32x4 o[4];
#pragma unroll
  for (int n = 0; n < 4; ++n) o[n] = (f32x4){0.f, 0.f, 0.f, 0.f};
  float mx = -1e30f, ls = 0.f;

  int buf = 0;
  for (int kv = 0; kv < NS; kv += 32, buf ^= 1) {
    const bf16* K0 = Kb + (long)(kv + c) * ND + g * 8;
    bf16x8 ka0 = *(const bf16x8*)(K0);
    bf16x8 ka1 = *(const bf16x8*)(K0 + 32);
    bf16x8 kb0 = *(const bf16x8*)(K0 + 16 * ND);
    bf16x8 kb1 = *(const bf16x8*)(K0 + 16 * ND + 32);
    f32x4 s0 = (f32x4){0.f, 0.f, 0.f, 0.f};
    f32x4 s1 = (f32x4){0.f, 0.f, 0.f, 0.f};
    s0 = __builtin_amdgcn_mfma_f32_16x16x32_bf16(ka0, qf0, s0, 0, 0, 0);
    s0 = __builtin_amdgcn_mfma_f32_16x16x32_bf16(ka1, qf1, s0, 0, 0, 0);
    s1 = __builtin_amdgcn_mfma_f32_16x16x32_bf16(kb0, qf0, s1, 0, 0, 0);
    s1 = __builtin_amdgcn_mfma_f32_16x16x32_bf16(kb1, qf1, s1, 0, 0, 0);

    // in-register softmax: lane holds 8 scores for q-row (qt*16+c)
    float pm = -1e30f;
#pragma unroll
    for (int r = 0; r < 4; ++r) {
      s0[r] *= 0.125f;
      s1[r] *= 0.125f;
      pm = fmaxf(pm, fmaxf(s0[r], s1[r]));
    }
    pm = fmaxf(pm, __shfl_xor(pm, 16));
    pm = fmaxf(pm, __shfl_xor(pm, 32));
    float mn = fmaxf(mx, pm);
    float sc = __expf(mx - mn);
    mx = mn;
    float p0[4], p1[4], rs = 0.f;
#pragma unroll
    for (int r = 0; r < 4; ++r) {
      p0[r] = __expf(s0[r] - mn);
      p1[r] = __expf(s1[r] - mn);
      rs += p0[r] + p1[r];
    }
    rs += __shfl_xor(rs, 16);
    rs += __shfl_xor(rs, 32);
    ls = ls * sc + rs;
#pragma unroll
    for (int nf = 0; nf < 4; ++nf)
#pragma unroll
      for (int r = 0; r < 4; ++r) o[nf][r] *= sc;

    bf16x4 w0, w1;
#pragma unroll
    for (int r = 0; r < 4; ++r) {
      w0[r] = (bf16)p0[r];
      w1[r] = (bf16)p1[r];
    }
    *(bf16x4*)&Pl[w][buf][c][4 * g] = w0;
    *(bf16x4*)&Pl[w][buf][c][16 + 4 * g] = w1;
    asm volatile("s_waitcnt lgkmcnt(0)" ::: "memory");
    __builtin_amdgcn_sched_barrier(0);
    bf16x8 pb = *(const bf16x8*)&Pl[w][buf][c][8 * g];

    const bf16* Vr = Vb + (long)c * NS + kv + g * 8;
#pragma unroll
    for (int nf = 0; nf < 4; ++nf) {
      bf16x8 va = *(const bf16x8*)(Vr + (long)(16 * nf) * NS);
      o[nf] = __builtin_amdgcn_mfma_f32_16x16x32_bf16(va, pb, o[nf], 0, 0, 0);
    }
  }

  float inv = 1.f / ls;
  bf16* Orow = O + (long)(b * NS + qt * 16 + c) * ND + h * NDK;
#pragma unroll
  for (int nf = 0; nf < 4; ++nf) {
    bf16x4 ov;
#pragma unroll
    for (int r = 0; r < 4; ++r) ov[r] = (bf16)(o[nf][r] * inv);
    *(bf16x4*)(Orow + 16 * nf + 4 * g) = ov;
  }
}

extern "C" void kernel_launch(void* const* d_in, const int* in_sizes, int n_in,
                              void* d_out, int out_size, void* d_ws, size_t ws_size,
                              hipStream_t stream) {
  (void)in_sizes; (void)n_in; (void)out_size; (void)ws_size;
  const float* x = (const float*)d_in[0];
  const float* y = (const float*)d_in[1];
  const float* x_pos = (const float*)d_in[2];
  const float* y_pos = (const float*)d_in[3];

  char* ws = (char*)d_ws;
  const size_t MB = 1ull << 20;
  bf16* Wt[8];
  for (int i = 0; i < 8; ++i) Wt[i] = (bf16*)(ws + (size_t)i * 2 * MB);
  bf16* W1T = (bf16*)(ws + 16 * MB);
  bf16* W2T = (bf16*)(ws + 24 * MB);
  float* xres = (float*)(ws + 32 * MB);
  bf16* x2 = (bf16*)(ws + 64 * MB);
  bf16* qk = (bf16*)(ws + 80 * MB);
  bf16* y2 = (bf16*)(ws + 96 * MB);
  bf16* yk = (bf16*)(ws + 112 * MB);
  bf16* Qb = (bf16*)(ws + 128 * MB);
  bf16* Kb = (bf16*)(ws + 144 * MB);
  bf16* Vb = (bf16*)(ws + 160 * MB);
  bf16* VTb = (bf16*)(ws + 176 * MB);
  bf16* Ob = (bf16*)(ws + 192 * MB);
  bf16* hb = (bf16*)(ws + 128 * MB);  // aliases Qb..VTb (free during FFN)

  dim3 tb(32, 8);
  for (int i = 0; i < 8; ++i)
    wconv_t<<<dim3(32, 32), tb, 0, stream>>>((const float*)d_in[4 + 2 * i], Wt[i], 1024, 1024);
  wconv_t<<<dim3(128, 32), tb, 0, stream>>>((const float*)d_in[20], W1T, 1024, 4096);
  wconv_t<<<dim3(32, 128), tb, 0, stream>>>((const float*)d_in[22], W2T, 4096, 1024);

  const float* ln1g = (const float*)d_in[24]; const float* ln1b = (const float*)d_in[25];
  const float* ln2g = (const float*)d_in[26]; const float* ln2b = (const float*)d_in[27];
  const float* ln3g = (const float*)d_in[28]; const float* ln3b = (const float*)d_in[29];
  const float* ln4g = (const float*)d_in[30]; const float* ln4b = (const float*)d_in[31];

  dim3 gD(8, 64);
  dim3 gF1(32, 64);
  dim3 gVT(32, 2, 128);
  dim3 gAT(16, 16, 8);

  // ---- self-attention ----
  ln_fused<<<8192, 256, 0, stream>>>(x, ln1g, ln1b, x_pos, x2, qk);
  gemm_bt<0><<<gD, 256, 0, stream>>>(qk, Wt[0], (const float*)d_in[5], nullptr, Qb, 8192, 1024, 1024);
  gemm_bt<0><<<gD, 256, 0, stream>>>(qk, Wt[1], (const float*)d_in[7], nullptr, Kb, 8192, 1024, 1024);
  gemm_bt<0><<<gD, 256, 0, stream>>>(x2, Wt[2], (const float*)d_in[9], nullptr, Vb, 8192, 1024, 1024);
  vtrans<<<gVT, tb, 0, stream>>>(Vb, VTb);
  attn_fwd<<<gAT, 256, 0, stream>>>(Qb, Kb, VTb, Ob);
  gemm_bt<1><<<gD, 256, 0, stream>>>(Ob, Wt[3], (const float*)d_in[11], x, xres, 8192, 1024, 1024);

  // ---- cross-attention ----
  ln_fused<<<8192, 256, 0, stream>>>(xres, ln2g, ln2b, x_pos, nullptr, qk);
  ln_fused<<<8192, 256, 0, stream>>>(y, ln3g, ln3b, y_pos, y2, yk);
  gemm_bt<0><<<gD, 256, 0, stream>>>(qk, Wt[4], (const float*)d_in[13], nullptr, Qb, 8192, 1024, 1024);
  gemm_bt<0><<<gD, 256, 0, stream>>>(yk, Wt[5], (const float*)d_in[15], nullptr, Kb, 8192, 1024, 1024);
  gemm_bt<0><<<gD, 256, 0, stream>>>(y2, Wt[6], (const float*)d_in[17], nullptr, Vb, 8192, 1024, 1024);
  vtrans<<<gVT, tb, 0, stream>>>(Vb, VTb);
  attn_fwd<<<gAT, 256, 0, stream>>>(Qb, Kb, VTb, Ob);
  gemm_bt<1><<<gD, 256, 0, stream>>>(Ob, Wt[7], (const float*)d_in[19], xres, xres, 8192, 1024, 1024);

  // ---- FFN ----
  ln_fused<<<8192, 256, 0, stream>>>(xres, ln4g, ln4b, nullptr, x2, nullptr);
  gemm_bt<2><<<gF1, 256, 0, stream>>>(x2, W1T, (const float*)d_in[21], nullptr, hb, 8192, 4096, 1024);
  gemm_bt<1><<<gD, 256, 0, stream>>>(hb, W2T, (const float*)d_in[23], xres, (float*)d_out, 8192, 1024, 4096);
}

// Round 3
// 806.625 us; speedup vs baseline: 1.4438x; 1.4427x over previous
//
#include <hip/hip_runtime.h>
#include <hip/hip_bf16.h>

#define NB 8
#define NS 1024
#define ND 1024
#define NH 16
#define NDK 64
#define NDFF 4096

typedef __bf16 bf16;
typedef __attribute__((ext_vector_type(8))) __bf16 bf16x8;
typedef __attribute__((ext_vector_type(4))) __bf16 bf16x4;
typedef __attribute__((ext_vector_type(4))) float f32x4;

__device__ __forceinline__ void gload16(const bf16* g, bf16* l) {
  __builtin_amdgcn_global_load_lds(
      (const __attribute__((address_space(1))) void*)g,
      (__attribute__((address_space(3))) void*)l, 16, 0, 0);
}

// ---- weight convert + transpose: W f32 [K][N] -> WT bf16 [N][K] ----
__global__ void wconv_t(const float* __restrict__ W, bf16* __restrict__ WT,
                        int K, int N) {
  __shared__ float tile[32][33];
  int n0 = blockIdx.x * 32, k0 = blockIdx.y * 32;
  int tx = threadIdx.x, ty = threadIdx.y;
#pragma unroll
  for (int i2 = 0; i2 < 4; ++i2) {
    int i = ty + i2 * 8;
    tile[i][tx] = W[(long)(k0 + i) * N + n0 + tx];
  }
  __syncthreads();
#pragma unroll
  for (int i2 = 0; i2 < 4; ++i2) {
    int i = ty + i2 * 8;
    WT[(long)(n0 + i) * K + k0 + tx] = (bf16)tile[tx][i];
  }
}

// ---- fused layernorm: out_ln = bf16(LN(x)), out_lnpos = bf16(LN(x)+pos) ----
__global__ void ln_fused(const float* __restrict__ in, const float* __restrict__ gam,
                         const float* __restrict__ bet, const float* __restrict__ pos,
                         bf16* __restrict__ out_ln, bf16* __restrict__ out_lnpos) {
  long row = blockIdx.x;
  int t = threadIdx.x;  // 256
  float4 v = ((const float4*)(in + row * ND))[t];
  float s = v.x + v.y + v.z + v.w;
  float s2 = v.x * v.x + v.y * v.y + v.z * v.z + v.w * v.w;
#pragma unroll
  for (int m = 32; m >= 1; m >>= 1) {
    s += __shfl_xor(s, m);
    s2 += __shfl_xor(s2, m);
  }
  __shared__ float red[8];
  if ((t & 63) == 0) {
    red[t >> 6] = s;
    red[4 + (t >> 6)] = s2;
  }
  __syncthreads();
  float ts = red[0] + red[1] + red[2] + red[3];
  float ts2 = red[4] + red[5] + red[6] + red[7];
  float mu = ts * (1.0f / ND);
  float var = ts2 * (1.0f / ND) - mu * mu;
  float rstd = rsqrtf(var + 1e-5f);
  float4 g4 = ((const float4*)gam)[t];
  float4 b4 = ((const float4*)bet)[t];
  float o0 = (v.x - mu) * rstd * g4.x + b4.x;
  float o1 = (v.y - mu) * rstd * g4.y + b4.y;
  float o2 = (v.z - mu) * rstd * g4.z + b4.z;
  float o3 = (v.w - mu) * rstd * g4.w + b4.w;
  if (out_ln) {
    bf16x4 q;
    q[0] = (bf16)o0; q[1] = (bf16)o1; q[2] = (bf16)o2; q[3] = (bf16)o3;
    *(bf16x4*)(out_ln + row * ND + t * 4) = q;
  }
  if (out_lnpos) {
    float4 p4 = ((const float4*)(pos + row * ND))[t];
    bf16x4 q;
    q[0] = (bf16)(o0 + p4.x); q[1] = (bf16)(o1 + p4.y);
    q[2] = (bf16)(o2 + p4.z); q[3] = (bf16)(o3 + p4.w);
    *(bf16x4*)(out_lnpos + row * ND + t * 4) = q;
  }
}

// ---- GEMM: C[M,N] = A[M,K] @ WT[N,K]^T + bias ; m97 structure (128x128, BK=32)
// blockIdx.x = M-tile (so blocks sharing an A-panel land on one XCD),
// blockIdx.y = N-tile.
// MODE 0: bf16 out.  MODE 1: f32 out = res + v.  MODE 2: bf16 out = swish(v).
template <int MODE>
__global__ __launch_bounds__(256) void gemm_bt(
    const bf16* __restrict__ A, const bf16* __restrict__ WT,
    const float* __restrict__ bias, const float* __restrict__ res,
    void* __restrict__ out, int M, int N, int K) {
  __shared__ bf16 As[128 * 32];
  __shared__ bf16 Bs[128 * 32];
  int t = threadIdx.x;
  int l = t & 63, w = t >> 6;
  int wr = w >> 1, wc = w & 1;
  int c16 = l & 15, g8 = (l >> 4) * 8;
  long row0 = (long)blockIdx.x * 128;
  long col0 = (long)blockIdx.y * 128;

  f32x4 acc[4][4];
#pragma unroll
  for (int m = 0; m < 4; ++m)
#pragma unroll
    for (int n = 0; n < 4; ++n) acc[m][n] = (f32x4){0.f, 0.f, 0.f, 0.f};

  const bf16* Ag = A + (row0 + (t >> 2)) * K + (t & 3) * 8;
  const bf16* Bg = WT + (col0 + (t >> 2)) * K + (t & 3) * 8;

  for (int k0 = 0; k0 < K; k0 += 32) {
    gload16(Ag + k0, &As[w * 512]);
    gload16(Ag + 64 * (long)K + k0, &As[2048 + w * 512]);
    gload16(Bg + k0, &Bs[w * 512]);
    gload16(Bg + 64 * (long)K + k0, &Bs[2048 + w * 512]);
    __syncthreads();
    bf16x8 a[4], b[4];
#pragma unroll
    for (int m = 0; m < 4; ++m)
      a[m] = *(const bf16x8*)&As[(wr * 64 + m * 16 + c16) * 32 + g8];
#pragma unroll
    for (int n = 0; n < 4; ++n)
      b[n] = *(const bf16x8*)&Bs[(wc * 64 + n * 16 + c16) * 32 + g8];
#pragma unroll
    for (int m = 0; m < 4; ++m)
#pragma unroll
      for (int n = 0; n < 4; ++n)
        acc[m][n] = __builtin_amdgcn_mfma_f32_16x16x32_bf16(a[m], b[n], acc[m][n], 0, 0, 0);
    __syncthreads();
  }

#pragma unroll
  for (int n = 0; n < 4; ++n) {
    long col = col0 + wc * 64 + n * 16 + c16;
    float bv = bias[col];
#pragma unroll
    for (int m = 0; m < 4; ++m) {
      long rowb = row0 + wr * 64 + m * 16 + (l >> 4) * 4;
#pragma unroll
      for (int r = 0; r < 4; ++r) {
        float v = acc[m][n][r] + bv;
        long idx = (rowb + r) * N + col;
        if (MODE == 0) {
          ((bf16*)out)[idx] = (bf16)v;
        } else if (MODE == 1) {
          ((float*)out)[idx] = res[idx] + v;
        } else {
          float sw = v / (1.f + __expf(-v));
          ((bf16*)out)[idx] = (bf16)sw;
        }
      }
    }
  }
}

// ---- V transpose per head: V [B*S][D] -> VT [B*H][DK][S] ----
__global__ void vtrans(const bf16* __restrict__ V, bf16* __restrict__ VT) {
  __shared__ bf16 tile[32][33];
  int st = blockIdx.x * 32, dt = blockIdx.y * 32;
  int bh = blockIdx.z;
  int b = bh >> 4, h = bh & 15;
  int tx = threadIdx.x, ty = threadIdx.y;
#pragma unroll
  for (int i2 = 0; i2 < 4; ++i2) {
    int i = ty + i2 * 8;
    tile[i][tx] = V[((long)b * NS + st + i) * ND + h * NDK + dt + tx];
  }
  __syncthreads();
#pragma unroll
  for (int i2 = 0; i2 < 4; ++i2) {
    int i = ty + i2 * 8;
    VT[((long)bh * NDK + dt + i) * NS + st + tx] = tile[tx][i];
  }
}

// ---- flash attention v3: LDS-staged K/VT (double-buffered, prefetch 1 tile),
// XOR-swizzled (T2), 128 q-rows/block (2 subtiles x 4 waves), KVBLK=64,
// swapped-operand softmax in-register, defer-max (T13), setprio (T5).
// Grid: 1024 blocks 1-D; bid = qt*128 + bh so blocks sharing (b,h) K/V
// differ by 128 == 0 mod 8 -> same XCD L2 (T1).
__global__ __launch_bounds__(256) void attn_fwd(
    const bf16* __restrict__ Q, const bf16* __restrict__ Kt,
    const bf16* __restrict__ VT, bf16* __restrict__ O) {
  __shared__ bf16 Ks[2][64 * 64];
  __shared__ bf16 Vs[2][64 * 64];
  __shared__ bf16 Pl[4][2][16 * 68];
  int t = threadIdx.x;
  int w = t >> 6, l = t & 63;
  int c = l & 15, g = l >> 4;
  int bid = blockIdx.x;
  int qt = bid >> 7, bh = bid & 127;
  int b = bh >> 4, h = bh & 15;
  int q0 = qt * 128 + w * 32;
  int swz = (c & 7) << 4;  // read-side byte-XOR within 128B rows

  // Q fragments (MFMA B-operand): qf[sub][dk-half]
  bf16x8 qf[2][2];
  const bf16* Qbase = Q + (long)(b * NS) * ND + h * NDK;
#pragma unroll
  for (int sj = 0; sj < 2; ++sj) {
    const bf16* qr = Qbase + (long)(q0 + sj * 16 + c) * ND + g * 8;
    qf[sj][0] = *(const bf16x8*)qr;
    qf[sj][1] = *(const bf16x8*)(qr + 32);
  }

  const bf16* Kg = Kt + (long)(b * NS) * ND + h * NDK;
  const bf16* Vg = VT + (long)(b * NH + h) * NDK * NS;

  // staging geometry: per instr j, 8 rows x 128B; source col pre-swizzled
  int sr = l >> 3;                     // row within 8-row group
  int sc8 = 8 * ((l & 7) ^ sr);        // pre-swizzled source col (elements)

  f32x4 o[2][4];
#pragma unroll
  for (int sj = 0; sj < 2; ++sj)
#pragma unroll
    for (int ds = 0; ds < 4; ++ds) o[sj][ds] = (f32x4){0.f, 0.f, 0.f, 0.f};
  float mx[2] = {-1e30f, -1e30f};
  float lsum[2] = {0.f, 0.f};

#define STAGE(BUF, KV)                                                        \
  {                                                                           \
    _Pragma("unroll") for (int j = 0; j < 2; ++j) {                           \
      int row = w * 16 + j * 8 + sr;                                          \
      gload16(Kg + (long)((KV) + row) * ND + sc8,                             \
              &Ks[BUF][(w * 16 + j * 8) * 64]);                               \
      gload16(Vg + (long)row * NS + (KV) + sc8,                               \
              &Vs[BUF][(w * 16 + j * 8) * 64]);                               \
    }                                                                         \
  }

  STAGE(0, 0);
  asm volatile("s_waitcnt vmcnt(0)" ::: "memory");
  __syncthreads();

  int buf = 0;
  for (int it = 0; it < NS / 64; ++it) {
    if (it + 1 < NS / 64) STAGE(buf ^ 1, (it + 1) * 64);

    // ---- QK^T (S^T frags: lane c = q-col, k = kt*16+4g+r) ----
    f32x4 sv[2][4];
#pragma unroll
    for (int sj = 0; sj < 2; ++sj)
#pragma unroll
      for (int kt = 0; kt < 4; ++kt) sv[sj][kt] = (f32x4){0.f, 0.f, 0.f, 0.f};
    __builtin_amdgcn_s_setprio(1);
#pragma unroll
    for (int kt = 0; kt < 4; ++kt) {
      const char* kr = (const char*)&Ks[buf][(kt * 16 + c) * 64];
      bf16x8 ka0 = *(const bf16x8*)(kr + ((g * 16) ^ swz));
      bf16x8 ka1 = *(const bf16x8*)(kr + ((64 + g * 16) ^ swz));
#pragma unroll
      for (int sj = 0; sj < 2; ++sj) {
        sv[sj][kt] = __builtin_amdgcn_mfma_f32_16x16x32_bf16(ka0, qf[sj][0], sv[sj][kt], 0, 0, 0);
        sv[sj][kt] = __builtin_amdgcn_mfma_f32_16x16x32_bf16(ka1, qf[sj][1], sv[sj][kt], 0, 0, 0);
      }
    }
    __builtin_amdgcn_s_setprio(0);

    // ---- softmax (in-register; reduce in-lane then xor 16,32) ----
    float pm[2];
#pragma unroll
    for (int sj = 0; sj < 2; ++sj) {
      float m = -1e30f;
#pragma unroll
      for (int kt = 0; kt < 4; ++kt)
#pragma unroll
        for (int r = 0; r < 4; ++r) {
          sv[sj][kt][r] *= 0.125f;
          m = fmaxf(m, sv[sj][kt][r]);
        }
      m = fmaxf(m, __shfl_xor(m, 16));
      m = fmaxf(m, __shfl_xor(m, 32));
      pm[sj] = m;
    }
    int cond = (pm[0] <= mx[0] + 8.f) && (pm[1] <= mx[1] + 8.f);
    if (!__all(cond)) {
#pragma unroll
      for (int sj = 0; sj < 2; ++sj) {
        float mn = fmaxf(mx[sj], pm[sj]);
        float sc = __expf(mx[sj] - mn);
        mx[sj] = mn;
        lsum[sj] *= sc;
#pragma unroll
        for (int ds = 0; ds < 4; ++ds)
#pragma unroll
          for (int r = 0; r < 4; ++r) o[sj][ds][r] *= sc;
      }
    }
#pragma unroll
    for (int sj = 0; sj < 2; ++sj) {
      float rs = 0.f;
#pragma unroll
      for (int kt = 0; kt < 4; ++kt) {
        bf16x4 pw;
#pragma unroll
        for (int r = 0; r < 4; ++r) {
          float e = __expf(sv[sj][kt][r] - mx[sj]);
          rs += e;
          pw[r] = (bf16)e;
        }
        *(bf16x4*)&Pl[w][sj][c * 68 + kt * 16 + 4 * g] = pw;
      }
      rs += __shfl_xor(rs, 16);
      rs += __shfl_xor(rs, 32);
      lsum[sj] += rs;
    }
    asm volatile("s_waitcnt lgkmcnt(0)" ::: "memory");
    __builtin_amdgcn_sched_barrier(0);

    // ---- PV (O^T frags: A = VT tile, B = P^T) ----
    __builtin_amdgcn_s_setprio(1);
#pragma unroll
    for (int ks = 0; ks < 2; ++ks) {
      bf16x8 pb0 = *(const bf16x8*)&Pl[w][0][c * 68 + ks * 32 + g * 8];
      bf16x8 pb1 = *(const bf16x8*)&Pl[w][1][c * 68 + ks * 32 + g * 8];
#pragma unroll
      for (int ds = 0; ds < 4; ++ds) {
        const char* vr = (const char*)&Vs[buf][(ds * 16 + c) * 64];
        bf16x8 va = *(const bf16x8*)(vr + ((ks * 64 + g * 16) ^ swz));
        o[0][ds] = __builtin_amdgcn_mfma_f32_16x16x32_bf16(va, pb0, o[0][ds], 0, 0, 0);
        o[1][ds] = __builtin_amdgcn_mfma_f32_16x16x32_bf16(va, pb1, o[1][ds], 0, 0, 0);
      }
    }
    __builtin_amdgcn_s_setprio(0);
    __syncthreads();  // drains vmcnt (prefetch) + lgkmcnt (P/V reads)
    buf ^= 1;
  }

#pragma unroll
  for (int sj = 0; sj < 2; ++sj) {
    float inv = 1.f / lsum[sj];
    bf16* Orow = O + (long)(b * NS + q0 + sj * 16 + c) * ND + h * NDK;
#pragma unroll
    for (int ds = 0; ds < 4; ++ds) {
      bf16x4 ov;
#pragma unroll
      for (int r = 0; r < 4; ++r) ov[r] = (bf16)(o[sj][ds][r] * inv);
      *(bf16x4*)(Orow + ds * 16 + 4 * g) = ov;
    }
  }
#undef STAGE
}

extern "C" void kernel_launch(void* const* d_in, const int* in_sizes, int n_in,
                              void* d_out, int out_size, void* d_ws, size_t ws_size,
                              hipStream_t stream) {
  (void)in_sizes; (void)n_in; (void)out_size; (void)ws_size;
  const float* x = (const float*)d_in[0];
  const float* y = (const float*)d_in[1];
  const float* x_pos = (const float*)d_in[2];
  const float* y_pos = (const float*)d_in[3];

  char* ws = (char*)d_ws;
  const size_t MB = 1ull << 20;
  bf16* Wt[8];
  for (int i = 0; i < 8; ++i) Wt[i] = (bf16*)(ws + (size_t)i * 2 * MB);
  bf16* W1T = (bf16*)(ws + 16 * MB);
  bf16* W2T = (bf16*)(ws + 24 * MB);
  float* xres = (float*)(ws + 32 * MB);
  bf16* x2 = (bf16*)(ws + 64 * MB);
  bf16* qk = (bf16*)(ws + 80 * MB);
  bf16* y2 = (bf16*)(ws + 96 * MB);
  bf16* yk = (bf16*)(ws + 112 * MB);
  bf16* Qb = (bf16*)(ws + 128 * MB);
  bf16* Kb = (bf16*)(ws + 144 * MB);
  bf16* Vb = (bf16*)(ws + 160 * MB);
  bf16* VTb = (bf16*)(ws + 176 * MB);
  bf16* Ob = (bf16*)(ws + 192 * MB);
  bf16* hb = (bf16*)(ws + 128 * MB);  // aliases Qb..VTb (free during FFN)

  dim3 tb(32, 8);
  for (int i = 0; i < 8; ++i)
    wconv_t<<<dim3(32, 32), tb, 0, stream>>>((const float*)d_in[4 + 2 * i], Wt[i], 1024, 1024);
  wconv_t<<<dim3(128, 32), tb, 0, stream>>>((const float*)d_in[20], W1T, 1024, 4096);
  wconv_t<<<dim3(32, 128), tb, 0, stream>>>((const float*)d_in[22], W2T, 4096, 1024);

  const float* ln1g = (const float*)d_in[24]; const float* ln1b = (const float*)d_in[25];
  const float* ln2g = (const float*)d_in[26]; const float* ln2b = (const float*)d_in[27];
  const float* ln3g = (const float*)d_in[28]; const float* ln3b = (const float*)d_in[29];
  const float* ln4g = (const float*)d_in[30]; const float* ln4b = (const float*)d_in[31];

  dim3 gD(64, 8);    // x = M-tiles, y = N-tiles
  dim3 gF1(64, 32);
  dim3 gVT(32, 2, 128);

  // ---- self-attention ----
  ln_fused<<<8192, 256, 0, stream>>>(x, ln1g, ln1b, x_pos, x2, qk);
  gemm_bt<0><<<gD, 256, 0, stream>>>(qk, Wt[0], (const float*)d_in[5], nullptr, Qb, 8192, 1024, 1024);
  gemm_bt<0><<<gD, 256, 0, stream>>>(qk, Wt[1], (const float*)d_in[7], nullptr, Kb, 8192, 1024, 1024);
  gemm_bt<0><<<gD, 256, 0, stream>>>(x2, Wt[2], (const float*)d_in[9], nullptr, Vb, 8192, 1024, 1024);
  vtrans<<<gVT, tb, 0, stream>>>(Vb, VTb);
  attn_fwd<<<1024, 256, 0, stream>>>(Qb, Kb, VTb, Ob);
  gemm_bt<1><<<gD, 256, 0, stream>>>(Ob, Wt[3], (const float*)d_in[11], x, xres, 8192, 1024, 1024);

  // ---- cross-attention ----
  ln_fused<<<8192, 256, 0, stream>>>(xres, ln2g, ln2b, x_pos, nullptr, qk);
  ln_fused<<<8192, 256, 0, stream>>>(y, ln3g, ln3b, y_pos, y2, yk);
  gemm_bt<0><<<gD, 256, 0, stream>>>(qk, Wt[4], (const float*)d_in[13], nullptr, Qb, 8192, 1024, 1024);
  gemm_bt<0><<<gD, 256, 0, stream>>>(yk, Wt[5], (const float*)d_in[15], nullptr, Kb, 8192, 1024, 1024);
  gemm_bt<0><<<gD, 256, 0, stream>>>(y2, Wt[6], (const float*)d_in[17], nullptr, Vb, 8192, 1024, 1024);
  vtrans<<<gVT, tb, 0, stream>>>(Vb, VTb);
  attn_fwd<<<1024, 256, 0, stream>>>(Qb, Kb, VTb, Ob);
  gemm_bt<1><<<gD, 256, 0, stream>>>(Ob, Wt[7], (const float*)d_in[19], xres, xres, 8192, 1024, 1024);

  // ---- FFN ----
  ln_fused<<<8192, 256, 0, stream>>>(xres, ln4g, ln4b, nullptr, x2, nullptr);
  gemm_bt<2><<<gF1, 256, 0, stream>>>(x2, W1T, (const float*)d_in[21], nullptr, hb, 8192, 4096, 1024);
  gemm_bt<1><<<gD, 256, 0, stream>>>(hb, W2T, (const float*)d_in[23], xres, (float*)d_out, 8192, 1024, 4096);
}

// Round 4
// 720.743 us; speedup vs baseline: 1.6158x; 1.1192x over previous
//
#include <hip/hip_runtime.h>
#include <hip/hip_bf16.h>

#define NB 8
#define NS 1024
#define ND 1024
#define NH 16
#define NDK 64
#define NDFF 4096

typedef __bf16 bf16;
typedef __attribute__((ext_vector_type(8))) __bf16 bf16x8;
typedef __attribute__((ext_vector_type(4))) __bf16 bf16x4;
typedef __attribute__((ext_vector_type(4))) float f32x4;

__device__ __forceinline__ void gload16(const bf16* g, bf16* l) {
  __builtin_amdgcn_global_load_lds(
      (const __attribute__((address_space(1))) void*)g,
      (__attribute__((address_space(3))) void*)l, 16, 0, 0);
}

// ---- weight convert + transpose: W f32 [K][N] -> WT bf16 [N][K] ----
__global__ void wconv_t(const float* __restrict__ W, bf16* __restrict__ WT,
                        int K, int N) {
  __shared__ float tile[32][33];
  int n0 = blockIdx.x * 32, k0 = blockIdx.y * 32;
  int tx = threadIdx.x, ty = threadIdx.y;
#pragma unroll
  for (int i2 = 0; i2 < 4; ++i2) {
    int i = ty + i2 * 8;
    tile[i][tx] = W[(long)(k0 + i) * N + n0 + tx];
  }
  __syncthreads();
#pragma unroll
  for (int i2 = 0; i2 < 4; ++i2) {
    int i = ty + i2 * 8;
    WT[(long)(n0 + i) * K + k0 + tx] = (bf16)tile[tx][i];
  }
}

// ---- fused layernorm: out_ln = bf16(LN(x)), out_lnpos = bf16(LN(x)+pos) ----
__global__ void ln_fused(const float* __restrict__ in, const float* __restrict__ gam,
                         const float* __restrict__ bet, const float* __restrict__ pos,
                         bf16* __restrict__ out_ln, bf16* __restrict__ out_lnpos) {
  long row = blockIdx.x;
  int t = threadIdx.x;  // 256
  float4 v = ((const float4*)(in + row * ND))[t];
  float s = v.x + v.y + v.z + v.w;
  float s2 = v.x * v.x + v.y * v.y + v.z * v.z + v.w * v.w;
#pragma unroll
  for (int m = 32; m >= 1; m >>= 1) {
    s += __shfl_xor(s, m);
    s2 += __shfl_xor(s2, m);
  }
  __shared__ float red[8];
  if ((t & 63) == 0) {
    red[t >> 6] = s;
    red[4 + (t >> 6)] = s2;
  }
  __syncthreads();
  float ts = red[0] + red[1] + red[2] + red[3];
  float ts2 = red[4] + red[5] + red[6] + red[7];
  float mu = ts * (1.0f / ND);
  float var = ts2 * (1.0f / ND) - mu * mu;
  float rstd = rsqrtf(var + 1e-5f);
  float4 g4 = ((const float4*)gam)[t];
  float4 b4 = ((const float4*)bet)[t];
  float o0 = (v.x - mu) * rstd * g4.x + b4.x;
  float o1 = (v.y - mu) * rstd * g4.y + b4.y;
  float o2 = (v.z - mu) * rstd * g4.z + b4.z;
  float o3 = (v.w - mu) * rstd * g4.w + b4.w;
  if (out_ln) {
    bf16x4 q;
    q[0] = (bf16)o0; q[1] = (bf16)o1; q[2] = (bf16)o2; q[3] = (bf16)o3;
    *(bf16x4*)(out_ln + row * ND + t * 4) = q;
  }
  if (out_lnpos) {
    float4 p4 = ((const float4*)(pos + row * ND))[t];
    bf16x4 q;
    q[0] = (bf16)(o0 + p4.x); q[1] = (bf16)(o1 + p4.y);
    q[2] = (bf16)(o2 + p4.z); q[3] = (bf16)(o3 + p4.w);
    *(bf16x4*)(out_lnpos + row * ND + t * 4) = q;
  }
}

// ---- GEMM v2: C[M,N] = A[M,K] @ WT[N,K]^T + bias.
// BM=256 BN=128 BK=64, 512 threads (8 waves 4Mx2N, 64x64 per wave).
// Triple-buffered LDS; stage tile t+2 while computing t; counted vmcnt(6)
// at tile boundary (T3+T4). XOR slot-swizzle both sides (T2). setprio (T5).
// MODE 0: bf16 out.  MODE 1: f32 out = res + v.  MODE 2: bf16 out = swish(v).
template <int MODE>
__global__ __launch_bounds__(512) void gemm_bt(
    const bf16* __restrict__ A, const bf16* __restrict__ WT,
    const float* __restrict__ bias, const float* __restrict__ res,
    void* __restrict__ out, int M, int N, int K) {
  __shared__ bf16 SA[3][256 * 64];  // 96 KiB
  __shared__ bf16 SB[3][128 * 64];  // 48 KiB
  const int t = threadIdx.x;
  const int w = t >> 6, l = t & 63;
  const int wr = w >> 1, wc = w & 1;
  const int c = l & 15, g = l >> 4, c7 = l & 7;
  const long row0 = (long)blockIdx.x * 256;
  const long col0 = (long)blockIdx.y * 128;
  const int NT = K >> 6;

  f32x4 acc[4][4];
#pragma unroll
  for (int m = 0; m < 4; ++m)
#pragma unroll
    for (int n = 0; n < 4; ++n) acc[m][n] = (f32x4){0.f, 0.f, 0.f, 0.f};

  // staging lane geometry: 8 rows x 8 slots of 16B per wave-instr;
  // source slot pre-swizzled (involution u ^= row&7) so LDS linear dest +
  // swizzled read = consistent (rule #21).
  const int lr = l >> 3;
  const int lu8 = ((l & 7) ^ lr) * 8;
  const bf16* Ag = A + (row0 + lr) * (long)K + lu8;
  const bf16* Bg = WT + (col0 + lr) * (long)K + lu8;

#define STG(PTR, SM, BS, RB, K0) \
  gload16((PTR) + (long)(RB) * K + (K0), &SM[BS][(RB)*64])
#define STAGE_H1(BS, K0)                \
  do {                                  \
    STG(Ag, SA, BS, w * 8, K0);         \
    STG(Ag, SA, BS, 64 + w * 8, K0);    \
    STG(Bg, SB, BS, w * 8, K0);         \
  } while (0)
#define STAGE_H2(BS, K0)                \
  do {                                  \
    STG(Ag, SA, BS, 128 + w * 8, K0);   \
    STG(Ag, SA, BS, 192 + w * 8, K0);   \
    STG(Bg, SB, BS, 64 + w * 8, K0);    \
  } while (0)

  // prologue: stage tiles 0 and 1 (12 loads in flight)
  STAGE_H1(0, 0);
  STAGE_H2(0, 0);
  STAGE_H1(1, 64);
  STAGE_H2(1, 64);

  for (int tt = 0; tt < NT; ++tt) {
    const int bc = tt % 3;
    const int bs = (tt + 2) % 3;
    const int kst = (tt + 2) << 6;
    const bool st = (tt + 2) < NT;
    // wait for tile tt's 6 loads (t+1's 6 remain in flight), then make
    // them visible to all waves.
    if (tt + 1 < NT) {
      asm volatile("s_waitcnt vmcnt(6)" ::: "memory");
    } else {
      asm volatile("s_waitcnt vmcnt(0)" ::: "memory");
    }
    __syncthreads();
#pragma unroll
    for (int ks = 0; ks < 2; ++ks) {
      bf16x8 af[4], bfr[4];
#pragma unroll
      for (int m = 0; m < 4; ++m)
        af[m] = *(const bf16x8*)((const char*)SA[bc] +
                 ((wr * 64 + m * 16 + c) * 128 + (((ks << 2) + g) ^ c7) * 16));
#pragma unroll
      for (int n = 0; n < 4; ++n)
        bfr[n] = *(const bf16x8*)((const char*)SB[bc] +
                 ((wc * 64 + n * 16 + c) * 128 + (((ks << 2) + g) ^ c7) * 16));
      if (st) {
        if (ks == 0) STAGE_H1(bs, kst);
        else STAGE_H2(bs, kst);
      }
      __builtin_amdgcn_s_barrier();
      asm volatile("s_waitcnt lgkmcnt(0)" ::: "memory");
      __builtin_amdgcn_sched_barrier(0);
      __builtin_amdgcn_s_setprio(1);
#pragma unroll
      for (int m = 0; m < 4; ++m)
#pragma unroll
        for (int n = 0; n < 4; ++n)
          acc[m][n] = __builtin_amdgcn_mfma_f32_16x16x32_bf16(af[m], bfr[n], acc[m][n], 0, 0, 0);
      __builtin_amdgcn_s_setprio(0);
      __builtin_amdgcn_s_barrier();
    }
  }
#undef STG
#undef STAGE_H1
#undef STAGE_H2

#pragma unroll
  for (int n = 0; n < 4; ++n) {
    const long col = col0 + wc * 64 + n * 16 + c;
    const float bv = bias[col];
#pragma unroll
    for (int m = 0; m < 4; ++m) {
      const long rowb = row0 + wr * 64 + m * 16 + g * 4;
#pragma unroll
      for (int r = 0; r < 4; ++r) {
        float v = acc[m][n][r] + bv;
        const long idx = (rowb + r) * N + col;
        if (MODE == 0) {
          ((bf16*)out)[idx] = (bf16)v;
        } else if (MODE == 1) {
          ((float*)out)[idx] = res[idx] + v;
        } else {
          float sw = v / (1.f + __expf(-v));
          ((bf16*)out)[idx] = (bf16)sw;
        }
      }
    }
  }
}

// ---- V transpose per head: V [B*S][D] -> VT [B*H][DK][S] ----
__global__ void vtrans(const bf16* __restrict__ V, bf16* __restrict__ VT) {
  __shared__ bf16 tile[32][33];
  int st = blockIdx.x * 32, dt = blockIdx.y * 32;
  int bh = blockIdx.z;
  int b = bh >> 4, h = bh & 15;
  int tx = threadIdx.x, ty = threadIdx.y;
#pragma unroll
  for (int i2 = 0; i2 < 4; ++i2) {
    int i = ty + i2 * 8;
    tile[i][tx] = V[((long)b * NS + st + i) * ND + h * NDK + dt + tx];
  }
  __syncthreads();
#pragma unroll
  for (int i2 = 0; i2 < 4; ++i2) {
    int i = ty + i2 * 8;
    VT[((long)bh * NDK + dt + i) * NS + st + tx] = tile[tx][i];
  }
}

// ---- flash attention v3 (unchanged from round 3) ----
__global__ __launch_bounds__(256) void attn_fwd(
    const bf16* __restrict__ Q, const bf16* __restrict__ Kt,
    const bf16* __restrict__ VT, bf16* __restrict__ O) {
  __shared__ bf16 Ks[2][64 * 64];
  __shared__ bf16 Vs[2][64 * 64];
  __shared__ bf16 Pl[4][2][16 * 68];
  int t = threadIdx.x;
  int w = t >> 6, l = t & 63;
  int c = l & 15, g = l >> 4;
  int bid = blockIdx.x;
  int qt = bid >> 7, bh = bid & 127;
  int b = bh >> 4, h = bh & 15;
  int q0 = qt * 128 + w * 32;
  int swz = (c & 7) << 4;

  bf16x8 qf[2][2];
  const bf16* Qbase = Q + (long)(b * NS) * ND + h * NDK;
#pragma unroll
  for (int sj = 0; sj < 2; ++sj) {
    const bf16* qr = Qbase + (long)(q0 + sj * 16 + c) * ND + g * 8;
    qf[sj][0] = *(const bf16x8*)qr;
    qf[sj][1] = *(const bf16x8*)(qr + 32);
  }

  const bf16* Kg = Kt + (long)(b * NS) * ND + h * NDK;
  const bf16* Vg = VT + (long)(b * NH + h) * NDK * NS;

  int sr = l >> 3;
  int sc8 = 8 * ((l & 7) ^ sr);

  f32x4 o[2][4];
#pragma unroll
  for (int sj = 0; sj < 2; ++sj)
#pragma unroll
    for (int ds = 0; ds < 4; ++ds) o[sj][ds] = (f32x4){0.f, 0.f, 0.f, 0.f};
  float mx[2] = {-1e30f, -1e30f};
  float lsum[2] = {0.f, 0.f};

#define STAGE(BUF, KV)                                                        \
  {                                                                           \
    _Pragma("unroll") for (int j = 0; j < 2; ++j) {                           \
      int row = w * 16 + j * 8 + sr;                                          \
      gload16(Kg + (long)((KV) + row) * ND + sc8,                             \
              &Ks[BUF][(w * 16 + j * 8) * 64]);                               \
      gload16(Vg + (long)row * NS + (KV) + sc8,                               \
              &Vs[BUF][(w * 16 + j * 8) * 64]);                               \
    }                                                                         \
  }

  STAGE(0, 0);
  asm volatile("s_waitcnt vmcnt(0)" ::: "memory");
  __syncthreads();

  int buf = 0;
  for (int it = 0; it < NS / 64; ++it) {
    if (it + 1 < NS / 64) STAGE(buf ^ 1, (it + 1) * 64);

    f32x4 sv[2][4];
#pragma unroll
    for (int sj = 0; sj < 2; ++sj)
#pragma unroll
      for (int kt = 0; kt < 4; ++kt) sv[sj][kt] = (f32x4){0.f, 0.f, 0.f, 0.f};
    __builtin_amdgcn_s_setprio(1);
#pragma unroll
    for (int kt = 0; kt < 4; ++kt) {
      const char* kr = (const char*)&Ks[buf][(kt * 16 + c) * 64];
      bf16x8 ka0 = *(const bf16x8*)(kr + ((g * 16) ^ swz));
      bf16x8 ka1 = *(const bf16x8*)(kr + ((64 + g * 16) ^ swz));
#pragma unroll
      for (int sj = 0; sj < 2; ++sj) {
        sv[sj][kt] = __builtin_amdgcn_mfma_f32_16x16x32_bf16(ka0, qf[sj][0], sv[sj][kt], 0, 0, 0);
        sv[sj][kt] = __builtin_amdgcn_mfma_f32_16x16x32_bf16(ka1, qf[sj][1], sv[sj][kt], 0, 0, 0);
      }
    }
    __builtin_amdgcn_s_setprio(0);

    float pm[2];
#pragma unroll
    for (int sj = 0; sj < 2; ++sj) {
      float m = -1e30f;
#pragma unroll
      for (int kt = 0; kt < 4; ++kt)
#pragma unroll
        for (int r = 0; r < 4; ++r) {
          sv[sj][kt][r] *= 0.125f;
          m = fmaxf(m, sv[sj][kt][r]);
        }
      m = fmaxf(m, __shfl_xor(m, 16));
      m = fmaxf(m, __shfl_xor(m, 32));
      pm[sj] = m;
    }
    int cond = (pm[0] <= mx[0] + 8.f) && (pm[1] <= mx[1] + 8.f);
    if (!__all(cond)) {
#pragma unroll
      for (int sj = 0; sj < 2; ++sj) {
        float mn = fmaxf(mx[sj], pm[sj]);
        float sc = __expf(mx[sj] - mn);
        mx[sj] = mn;
        lsum[sj] *= sc;
#pragma unroll
        for (int ds = 0; ds < 4; ++ds)
#pragma unroll
          for (int r = 0; r < 4; ++r) o[sj][ds][r] *= sc;
      }
    }
#pragma unroll
    for (int sj = 0; sj < 2; ++sj) {
      float rs = 0.f;
#pragma unroll
      for (int kt = 0; kt < 4; ++kt) {
        bf16x4 pw;
#pragma unroll
        for (int r = 0; r < 4; ++r) {
          float e = __expf(sv[sj][kt][r] - mx[sj]);
          rs += e;
          pw[r] = (bf16)e;
        }
        *(bf16x4*)&Pl[w][sj][c * 68 + kt * 16 + 4 * g] = pw;
      }
      rs += __shfl_xor(rs, 16);
      rs += __shfl_xor(rs, 32);
      lsum[sj] += rs;
    }
    asm volatile("s_waitcnt lgkmcnt(0)" ::: "memory");
    __builtin_amdgcn_sched_barrier(0);

    __builtin_amdgcn_s_setprio(1);
#pragma unroll
    for (int ks = 0; ks < 2; ++ks) {
      bf16x8 pb0 = *(const bf16x8*)&Pl[w][0][c * 68 + ks * 32 + g * 8];
      bf16x8 pb1 = *(const bf16x8*)&Pl[w][1][c * 68 + ks * 32 + g * 8];
#pragma unroll
      for (int ds = 0; ds < 4; ++ds) {
        const char* vr = (const char*)&Vs[buf][(ds * 16 + c) * 64];
        bf16x8 va = *(const bf16x8*)(vr + ((ks * 64 + g * 16) ^ swz));
        o[0][ds] = __builtin_amdgcn_mfma_f32_16x16x32_bf16(va, pb0, o[0][ds], 0, 0, 0);
        o[1][ds] = __builtin_amdgcn_mfma_f32_16x16x32_bf16(va, pb1, o[1][ds], 0, 0, 0);
      }
    }
    __builtin_amdgcn_s_setprio(0);
    __syncthreads();
    buf ^= 1;
  }

#pragma unroll
  for (int sj = 0; sj < 2; ++sj) {
    float inv = 1.f / lsum[sj];
    bf16* Orow = O + (long)(b * NS + q0 + sj * 16 + c) * ND + h * NDK;
#pragma unroll
    for (int ds = 0; ds < 4; ++ds) {
      bf16x4 ov;
#pragma unroll
      for (int r = 0; r < 4; ++r) ov[r] = (bf16)(o[sj][ds][r] * inv);
      *(bf16x4*)(Orow + ds * 16 + 4 * g) = ov;
    }
  }
#undef STAGE
}

extern "C" void kernel_launch(void* const* d_in, const int* in_sizes, int n_in,
                              void* d_out, int out_size, void* d_ws, size_t ws_size,
                              hipStream_t stream) {
  (void)in_sizes; (void)n_in; (void)out_size; (void)ws_size;
  const float* x = (const float*)d_in[0];
  const float* y = (const float*)d_in[1];
  const float* x_pos = (const float*)d_in[2];
  const float* y_pos = (const float*)d_in[3];

  char* ws = (char*)d_ws;
  const size_t MB = 1ull << 20;
  bf16* Wt[8];
  for (int i = 0; i < 8; ++i) Wt[i] = (bf16*)(ws + (size_t)i * 2 * MB);
  bf16* W1T = (bf16*)(ws + 16 * MB);
  bf16* W2T = (bf16*)(ws + 24 * MB);
  float* xres = (float*)(ws + 32 * MB);
  bf16* x2 = (bf16*)(ws + 64 * MB);
  bf16* qk = (bf16*)(ws + 80 * MB);
  bf16* y2 = (bf16*)(ws + 96 * MB);
  bf16* yk = (bf16*)(ws + 112 * MB);
  bf16* Qb = (bf16*)(ws + 128 * MB);
  bf16* Kb = (bf16*)(ws + 144 * MB);
  bf16* Vb = (bf16*)(ws + 160 * MB);
  bf16* VTb = (bf16*)(ws + 176 * MB);
  bf16* Ob = (bf16*)(ws + 192 * MB);
  bf16* hb = (bf16*)(ws + 128 * MB);  // aliases Qb..VTb (free during FFN)

  dim3 tb(32, 8);
  for (int i = 0; i < 8; ++i)
    wconv_t<<<dim3(32, 32), tb, 0, stream>>>((const float*)d_in[4 + 2 * i], Wt[i], 1024, 1024);
  wconv_t<<<dim3(128, 32), tb, 0, stream>>>((const float*)d_in[20], W1T, 1024, 4096);
  wconv_t<<<dim3(32, 128), tb, 0, stream>>>((const float*)d_in[22], W2T, 4096, 1024);

  const float* ln1g = (const float*)d_in[24]; const float* ln1b = (const float*)d_in[25];
  const float* ln2g = (const float*)d_in[26]; const float* ln2b = (const float*)d_in[27];
  const float* ln3g = (const float*)d_in[28]; const float* ln3b = (const float*)d_in[29];
  const float* ln4g = (const float*)d_in[30]; const float* ln4b = (const float*)d_in[31];

  dim3 gD(32, 8);    // M-tiles(256) x N-tiles(128)
  dim3 gF1(32, 32);
  dim3 gVT(32, 2, 128);

  // ---- self-attention ----
  ln_fused<<<8192, 256, 0, stream>>>(x, ln1g, ln1b, x_pos, x2, qk);
  gemm_bt<0><<<gD, 512, 0, stream>>>(qk, Wt[0], (const float*)d_in[5], nullptr, Qb, 8192, 1024, 1024);
  gemm_bt<0><<<gD, 512, 0, stream>>>(qk, Wt[1], (const float*)d_in[7], nullptr, Kb, 8192, 1024, 1024);
  gemm_bt<0><<<gD, 512, 0, stream>>>(x2, Wt[2], (const float*)d_in[9], nullptr, Vb, 8192, 1024, 1024);
  vtrans<<<gVT, tb, 0, stream>>>(Vb, VTb);
  attn_fwd<<<1024, 256, 0, stream>>>(Qb, Kb, VTb, Ob);
  gemm_bt<1><<<gD, 512, 0, stream>>>(Ob, Wt[3], (const float*)d_in[11], x, xres, 8192, 1024, 1024);

  // ---- cross-attention ----
  ln_fused<<<8192, 256, 0, stream>>>(xres, ln2g, ln2b, x_pos, nullptr, qk);
  ln_fused<<<8192, 256, 0, stream>>>(y, ln3g, ln3b, y_pos, y2, yk);
  gemm_bt<0><<<gD, 512, 0, stream>>>(qk, Wt[4], (const float*)d_in[13], nullptr, Qb, 8192, 1024, 1024);
  gemm_bt<0><<<gD, 512, 0, stream>>>(yk, Wt[5], (const float*)d_in[15], nullptr, Kb, 8192, 1024, 1024);
  gemm_bt<0><<<gD, 512, 0, stream>>>(y2, Wt[6], (const float*)d_in[17], nullptr, Vb, 8192, 1024, 1024);
  vtrans<<<gVT, tb, 0, stream>>>(Vb, VTb);
  attn_fwd<<<1024, 256, 0, stream>>>(Qb, Kb, VTb, Ob);
  gemm_bt<1><<<gD, 512, 0, stream>>>(Ob, Wt[7], (const float*)d_in[19], xres, xres, 8192, 1024, 1024);

  // ---- FFN ----
  ln_fused<<<8192, 256, 0, stream>>>(xres, ln4g, ln4b, nullptr, x2, nullptr);
  gemm_bt<2><<<gF1, 512, 0, stream>>>(x2, W1T, (const float*)d_in[21], nullptr, hb, 8192, 4096, 1024);
  gemm_bt<1><<<gD, 512, 0, stream>>>(hb, W2T, (const float*)d_in[23], xres, (float*)d_out, 8192, 1024, 4096);
}

// Round 5
// 698.814 us; speedup vs baseline: 1.6665x; 1.0314x over previous
//
#include <hip/hip_runtime.h>
#include <hip/hip_bf16.h>

#define NB 8
#define NS 1024
#define ND 1024
#define NH 16
#define NDK 64
#define NDFF 4096

typedef __bf16 bf16;
typedef __attribute__((ext_vector_type(8))) __bf16 bf16x8;
typedef __attribute__((ext_vector_type(4))) __bf16 bf16x4;
typedef __attribute__((ext_vector_type(4))) float f32x4;

__device__ __forceinline__ void gload16(const bf16* g, bf16* l) {
  __builtin_amdgcn_global_load_lds(
      (const __attribute__((address_space(1))) void*)g,
      (__attribute__((address_space(3))) void*)l, 16, 0, 0);
}

// ---- weight convert + transpose: W f32 [K][N] -> WT bf16 [N][K] ----
__global__ void wconv_t(const float* __restrict__ W, bf16* __restrict__ WT,
                        int K, int N) {
  __shared__ float tile[32][33];
  int n0 = blockIdx.x * 32, k0 = blockIdx.y * 32;
  int tx = threadIdx.x, ty = threadIdx.y;
#pragma unroll
  for (int i2 = 0; i2 < 4; ++i2) {
    int i = ty + i2 * 8;
    tile[i][tx] = W[(long)(k0 + i) * N + n0 + tx];
  }
  __syncthreads();
#pragma unroll
  for (int i2 = 0; i2 < 4; ++i2) {
    int i = ty + i2 * 8;
    WT[(long)(n0 + i) * K + k0 + tx] = (bf16)tile[tx][i];
  }
}

// ---- fused layernorm: out_ln = bf16(LN(x)), out_lnpos = bf16(LN(x)+pos) ----
__global__ void ln_fused(const float* __restrict__ in, const float* __restrict__ gam,
                         const float* __restrict__ bet, const float* __restrict__ pos,
                         bf16* __restrict__ out_ln, bf16* __restrict__ out_lnpos) {
  long row = blockIdx.x;
  int t = threadIdx.x;  // 256
  float4 v = ((const float4*)(in + row * ND))[t];
  float s = v.x + v.y + v.z + v.w;
  float s2 = v.x * v.x + v.y * v.y + v.z * v.z + v.w * v.w;
#pragma unroll
  for (int m = 32; m >= 1; m >>= 1) {
    s += __shfl_xor(s, m);
    s2 += __shfl_xor(s2, m);
  }
  __shared__ float red[8];
  if ((t & 63) == 0) {
    red[t >> 6] = s;
    red[4 + (t >> 6)] = s2;
  }
  __syncthreads();
  float ts = red[0] + red[1] + red[2] + red[3];
  float ts2 = red[4] + red[5] + red[6] + red[7];
  float mu = ts * (1.0f / ND);
  float var = ts2 * (1.0f / ND) - mu * mu;
  float rstd = rsqrtf(var + 1e-5f);
  float4 g4 = ((const float4*)gam)[t];
  float4 b4 = ((const float4*)bet)[t];
  float o0 = (v.x - mu) * rstd * g4.x + b4.x;
  float o1 = (v.y - mu) * rstd * g4.y + b4.y;
  float o2 = (v.z - mu) * rstd * g4.z + b4.z;
  float o3 = (v.w - mu) * rstd * g4.w + b4.w;
  if (out_ln) {
    bf16x4 q;
    q[0] = (bf16)o0; q[1] = (bf16)o1; q[2] = (bf16)o2; q[3] = (bf16)o3;
    *(bf16x4*)(out_ln + row * ND + t * 4) = q;
  }
  if (out_lnpos) {
    float4 p4 = ((const float4*)(pos + row * ND))[t];
    bf16x4 q;
    q[0] = (bf16)(o0 + p4.x); q[1] = (bf16)(o1 + p4.y);
    q[2] = (bf16)(o2 + p4.z); q[3] = (bf16)(o3 + p4.w);
    *(bf16x4*)(out_lnpos + row * ND + t * 4) = q;
  }
}

// ---- GEMM v3: C[M,N] = A[M,K] @ WT[N,K]^T + bias.
// BM=256 BN=128 BK=32, 512 thr (8 waves 4Mx2N, 64x64/wave).
// 5-slot LDS pipeline, 4 K-tiles in flight, counted vmcnt(9) (T3+T4).
// One phase per K-tile: {8 ds_read | stage t+4 (3 gload) | bar | 16 MFMA}.
// Slot swizzle: store col 8*((l&3)^((l>>3)&3)); read slot g^((c>>1)&3) -> 2-way (free).
// MODE 0: bf16 out.  MODE 1: f32 out = res + v.  MODE 2: bf16 out = swish(v).
template <int MODE>
__global__ __launch_bounds__(512, 2) void gemm_bt(
    const bf16* __restrict__ A, const bf16* __restrict__ WT,
    const float* __restrict__ bias, const float* __restrict__ res,
    void* __restrict__ out, int M, int N, int K) {
  __shared__ bf16 SA[5][256 * 32];  // 80 KiB
  __shared__ bf16 SB[5][128 * 32];  // 40 KiB
  const int t = threadIdx.x;
  const int w = t >> 6, l = t & 63;
  const int wr = w >> 2, wc = w & 3;     // 2M x 4N? no: 4M x 2N below
  const int wrm = w >> 1, wcn = w & 1;   // 4M x 2N: rows wrm*64, cols wcn*64
  (void)wr; (void)wc;
  const int c = l & 15, g = l >> 4;
  const long row0 = (long)blockIdx.x * 256;
  const long col0 = (long)blockIdx.y * 128;
  const int NT = K >> 5;

  f32x4 acc[4][4];
#pragma unroll
  for (int m = 0; m < 4; ++m)
#pragma unroll
    for (int n = 0; n < 4; ++n) acc[m][n] = (f32x4){0.f, 0.f, 0.f, 0.f};

  // staging lane geometry: row_off = l>>2 (16 rows/instr), store-swizzled col
  const int lr = l >> 2;
  const int lcol = 8 * ((l & 3) ^ ((l >> 3) & 3));
  const bf16* Ag0 = A + (row0 + w * 32 + lr) * (long)K + lcol;
  const bf16* Ag1 = Ag0 + 16 * (long)K;
  const bf16* Bg0 = WT + (col0 + w * 16 + lr) * (long)K + lcol;

#define STAGE(BS, KK)                              \
  do {                                             \
    gload16(Ag0 + (KK), &SA[BS][(w * 32) * 32]);   \
    gload16(Ag1 + (KK), &SA[BS][(w * 32 + 16) * 32]); \
    gload16(Bg0 + (KK), &SB[BS][(w * 16) * 32]);   \
  } while (0)

  // prologue: stage tiles 0..3 (12 loads in flight)
  STAGE(0, 0);
  STAGE(1, 32);
  STAGE(2, 64);
  STAGE(3, 96);

  // per-frag LDS element offsets (loop-invariant)
  const int swz8 = (g ^ ((c >> 1) & 3)) * 8;
  int aoff[4], boff[4];
#pragma unroll
  for (int m = 0; m < 4; ++m) aoff[m] = (wrm * 64 + m * 16 + c) * 32 + swz8;
#pragma unroll
  for (int n = 0; n < 4; ++n) boff[n] = (wcn * 64 + n * 16 + c) * 32 + swz8;

  int cb = 0, sb = 4;
  int ks_off = 128;  // k-elem offset of tile t+4
  for (int tt = 0; tt < NT; ++tt) {
    const int rem = NT - 1 - tt;
    if (rem >= 3) {
      asm volatile("s_waitcnt vmcnt(9)" ::: "memory");
    } else if (rem == 2) {
      asm volatile("s_waitcnt vmcnt(6)" ::: "memory");
    } else if (rem == 1) {
      asm volatile("s_waitcnt vmcnt(3)" ::: "memory");
    } else {
      asm volatile("s_waitcnt vmcnt(0)" ::: "memory");
    }
    __builtin_amdgcn_s_barrier();

    const int ca = cb * (256 * 32);
    const int cbb = cb * (128 * 32);
    bf16x8 af[4], bfr[4];
#pragma unroll
    for (int m = 0; m < 4; ++m) af[m] = *(const bf16x8*)&SA[0][ca + aoff[m]];
#pragma unroll
    for (int n = 0; n < 4; ++n) bfr[n] = *(const bf16x8*)&SB[0][cbb + boff[n]];

    if (tt + 4 < NT) STAGE(sb, ks_off);

    __builtin_amdgcn_s_barrier();
    __builtin_amdgcn_s_setprio(1);
#pragma unroll
    for (int m = 0; m < 4; ++m)
#pragma unroll
      for (int n = 0; n < 4; ++n)
        acc[m][n] = __builtin_amdgcn_mfma_f32_16x16x32_bf16(af[m], bfr[n], acc[m][n], 0, 0, 0);
    __builtin_amdgcn_s_setprio(0);

    cb = (cb == 4) ? 0 : cb + 1;
    sb = (sb == 4) ? 0 : sb + 1;
    ks_off += 32;
  }
#undef STAGE

#pragma unroll
  for (int n = 0; n < 4; ++n) {
    const long col = col0 + wcn * 64 + n * 16 + c;
    const float bv = bias[col];
#pragma unroll
    for (int m = 0; m < 4; ++m) {
      const long rowb = row0 + wrm * 64 + m * 16 + g * 4;
#pragma unroll
      for (int r = 0; r < 4; ++r) {
        float v = acc[m][n][r] + bv;
        const long idx = (rowb + r) * N + col;
        if (MODE == 0) {
          ((bf16*)out)[idx] = (bf16)v;
        } else if (MODE == 1) {
          ((float*)out)[idx] = res[idx] + v;
        } else {
          float sw = v / (1.f + __expf(-v));
          ((bf16*)out)[idx] = (bf16)sw;
        }
      }
    }
  }
}

// ---- V transpose per head: V [B*S][D] -> VT [B*H][DK][S] ----
__global__ void vtrans(const bf16* __restrict__ V, bf16* __restrict__ VT) {
  __shared__ bf16 tile[32][33];
  int st = blockIdx.x * 32, dt = blockIdx.y * 32;
  int bh = blockIdx.z;
  int b = bh >> 4, h = bh & 15;
  int tx = threadIdx.x, ty = threadIdx.y;
#pragma unroll
  for (int i2 = 0; i2 < 4; ++i2) {
    int i = ty + i2 * 8;
    tile[i][tx] = V[((long)b * NS + st + i) * ND + h * NDK + dt + tx];
  }
  __syncthreads();
#pragma unroll
  for (int i2 = 0; i2 < 4; ++i2) {
    int i = ty + i2 * 8;
    VT[((long)bh * NDK + dt + i) * NS + st + tx] = tile[tx][i];
  }
}

// ---- flash attention v3 (unchanged) ----
__global__ __launch_bounds__(256) void attn_fwd(
    const bf16* __restrict__ Q, const bf16* __restrict__ Kt,
    const bf16* __restrict__ VT, bf16* __restrict__ O) {
  __shared__ bf16 Ks[2][64 * 64];
  __shared__ bf16 Vs[2][64 * 64];
  __shared__ bf16 Pl[4][2][16 * 68];
  int t = threadIdx.x;
  int w = t >> 6, l = t & 63;
  int c = l & 15, g = l >> 4;
  int bid = blockIdx.x;
  int qt = bid >> 7, bh = bid & 127;
  int b = bh >> 4, h = bh & 15;
  int q0 = qt * 128 + w * 32;
  int swz = (c & 7) << 4;

  bf16x8 qf[2][2];
  const bf16* Qbase = Q + (long)(b * NS) * ND + h * NDK;
#pragma unroll
  for (int sj = 0; sj < 2; ++sj) {
    const bf16* qr = Qbase + (long)(q0 + sj * 16 + c) * ND + g * 8;
    qf[sj][0] = *(const bf16x8*)qr;
    qf[sj][1] = *(const bf16x8*)(qr + 32);
  }

  const bf16* Kg = Kt + (long)(b * NS) * ND + h * NDK;
  const bf16* Vg = VT + (long)(b * NH + h) * NDK * NS;

  int sr = l >> 3;
  int sc8 = 8 * ((l & 7) ^ sr);

  f32x4 o[2][4];
#pragma unroll
  for (int sj = 0; sj < 2; ++sj)
#pragma unroll
    for (int ds = 0; ds < 4; ++ds) o[sj][ds] = (f32x4){0.f, 0.f, 0.f, 0.f};
  float mx[2] = {-1e30f, -1e30f};
  float lsum[2] = {0.f, 0.f};

#define STAGE(BUF, KV)                                                        \
  {                                                                           \
    _Pragma("unroll") for (int j = 0; j < 2; ++j) {                           \
      int row = w * 16 + j * 8 + sr;                                          \
      gload16(Kg + (long)((KV) + row) * ND + sc8,                             \
              &Ks[BUF][(w * 16 + j * 8) * 64]);                               \
      gload16(Vg + (long)row * NS + (KV) + sc8,                               \
              &Vs[BUF][(w * 16 + j * 8) * 64]);                               \
    }                                                                         \
  }

  STAGE(0, 0);
  asm volatile("s_waitcnt vmcnt(0)" ::: "memory");
  __syncthreads();

  int buf = 0;
  for (int it = 0; it < NS / 64; ++it) {
    if (it + 1 < NS / 64) STAGE(buf ^ 1, (it + 1) * 64);

    f32x4 sv[2][4];
#pragma unroll
    for (int sj = 0; sj < 2; ++sj)
#pragma unroll
      for (int kt = 0; kt < 4; ++kt) sv[sj][kt] = (f32x4){0.f, 0.f, 0.f, 0.f};
    __builtin_amdgcn_s_setprio(1);
#pragma unroll
    for (int kt = 0; kt < 4; ++kt) {
      const char* kr = (const char*)&Ks[buf][(kt * 16 + c) * 64];
      bf16x8 ka0 = *(const bf16x8*)(kr + ((g * 16) ^ swz));
      bf16x8 ka1 = *(const bf16x8*)(kr + ((64 + g * 16) ^ swz));
#pragma unroll
      for (int sj = 0; sj < 2; ++sj) {
        sv[sj][kt] = __builtin_amdgcn_mfma_f32_16x16x32_bf16(ka0, qf[sj][0], sv[sj][kt], 0, 0, 0);
        sv[sj][kt] = __builtin_amdgcn_mfma_f32_16x16x32_bf16(ka1, qf[sj][1], sv[sj][kt], 0, 0, 0);
      }
    }
    __builtin_amdgcn_s_setprio(0);

    float pm[2];
#pragma unroll
    for (int sj = 0; sj < 2; ++sj) {
      float m = -1e30f;
#pragma unroll
      for (int kt = 0; kt < 4; ++kt)
#pragma unroll
        for (int r = 0; r < 4; ++r) {
          sv[sj][kt][r] *= 0.125f;
          m = fmaxf(m, sv[sj][kt][r]);
        }
      m = fmaxf(m, __shfl_xor(m, 16));
      m = fmaxf(m, __shfl_xor(m, 32));
      pm[sj] = m;
    }
    int cond = (pm[0] <= mx[0] + 8.f) && (pm[1] <= mx[1] + 8.f);
    if (!__all(cond)) {
#pragma unroll
      for (int sj = 0; sj < 2; ++sj) {
        float mn = fmaxf(mx[sj], pm[sj]);
        float sc = __expf(mx[sj] - mn);
        mx[sj] = mn;
        lsum[sj] *= sc;
#pragma unroll
        for (int ds = 0; ds < 4; ++ds)
#pragma unroll
          for (int r = 0; r < 4; ++r) o[sj][ds][r] *= sc;
      }
    }
#pragma unroll
    for (int sj = 0; sj < 2; ++sj) {
      float rs = 0.f;
#pragma unroll
      for (int kt = 0; kt < 4; ++kt) {
        bf16x4 pw;
#pragma unroll
        for (int r = 0; r < 4; ++r) {
          float e = __expf(sv[sj][kt][r] - mx[sj]);
          rs += e;
          pw[r] = (bf16)e;
        }
        *(bf16x4*)&Pl[w][sj][c * 68 + kt * 16 + 4 * g] = pw;
      }
      rs += __shfl_xor(rs, 16);
      rs += __shfl_xor(rs, 32);
      lsum[sj] += rs;
    }
    asm volatile("s_waitcnt lgkmcnt(0)" ::: "memory");
    __builtin_amdgcn_sched_barrier(0);

    __builtin_amdgcn_s_setprio(1);
#pragma unroll
    for (int ks = 0; ks < 2; ++ks) {
      bf16x8 pb0 = *(const bf16x8*)&Pl[w][0][c * 68 + ks * 32 + g * 8];
      bf16x8 pb1 = *(const bf16x8*)&Pl[w][1][c * 68 + ks * 32 + g * 8];
#pragma unroll
      for (int ds = 0; ds < 4; ++ds) {
        const char* vr = (const char*)&Vs[buf][(ds * 16 + c) * 64];
        bf16x8 va = *(const bf16x8*)(vr + ((ks * 64 + g * 16) ^ swz));
        o[0][ds] = __builtin_amdgcn_mfma_f32_16x16x32_bf16(va, pb0, o[0][ds], 0, 0, 0);
        o[1][ds] = __builtin_amdgcn_mfma_f32_16x16x32_bf16(va, pb1, o[1][ds], 0, 0, 0);
      }
    }
    __builtin_amdgcn_s_setprio(0);
    __syncthreads();
    buf ^= 1;
  }

#pragma unroll
  for (int sj = 0; sj < 2; ++sj) {
    float inv = 1.f / lsum[sj];
    bf16* Orow = O + (long)(b * NS + q0 + sj * 16 + c) * ND + h * NDK;
#pragma unroll
    for (int ds = 0; ds < 4; ++ds) {
      bf16x4 ov;
#pragma unroll
      for (int r = 0; r < 4; ++r) ov[r] = (bf16)(o[sj][ds][r] * inv);
      *(bf16x4*)(Orow + ds * 16 + 4 * g) = ov;
    }
  }
#undef STAGE
}

extern "C" void kernel_launch(void* const* d_in, const int* in_sizes, int n_in,
                              void* d_out, int out_size, void* d_ws, size_t ws_size,
                              hipStream_t stream) {
  (void)in_sizes; (void)n_in; (void)out_size; (void)ws_size;
  const float* x = (const float*)d_in[0];
  const float* y = (const float*)d_in[1];
  const float* x_pos = (const float*)d_in[2];
  const float* y_pos = (const float*)d_in[3];

  char* ws = (char*)d_ws;
  const size_t MB = 1ull << 20;
  bf16* Wt[8];
  for (int i = 0; i < 8; ++i) Wt[i] = (bf16*)(ws + (size_t)i * 2 * MB);
  bf16* W1T = (bf16*)(ws + 16 * MB);
  bf16* W2T = (bf16*)(ws + 24 * MB);
  float* xres = (float*)(ws + 32 * MB);
  bf16* x2 = (bf16*)(ws + 64 * MB);
  bf16* qk = (bf16*)(ws + 80 * MB);
  bf16* y2 = (bf16*)(ws + 96 * MB);
  bf16* yk = (bf16*)(ws + 112 * MB);
  bf16* Qb = (bf16*)(ws + 128 * MB);
  bf16* Kb = (bf16*)(ws + 144 * MB);
  bf16* Vb = (bf16*)(ws + 160 * MB);
  bf16* VTb = (bf16*)(ws + 176 * MB);
  bf16* Ob = (bf16*)(ws + 192 * MB);
  bf16* hb = (bf16*)(ws + 128 * MB);  // aliases Qb..VTb (free during FFN)

  dim3 tb(32, 8);
  for (int i = 0; i < 8; ++i)
    wconv_t<<<dim3(32, 32), tb, 0, stream>>>((const float*)d_in[4 + 2 * i], Wt[i], 1024, 1024);
  wconv_t<<<dim3(128, 32), tb, 0, stream>>>((const float*)d_in[20], W1T, 1024, 4096);
  wconv_t<<<dim3(32, 128), tb, 0, stream>>>((const float*)d_in[22], W2T, 4096, 1024);

  const float* ln1g = (const float*)d_in[24]; const float* ln1b = (const float*)d_in[25];
  const float* ln2g = (const float*)d_in[26]; const float* ln2b = (const float*)d_in[27];
  const float* ln3g = (const float*)d_in[28]; const float* ln3b = (const float*)d_in[29];
  const float* ln4g = (const float*)d_in[30]; const float* ln4b = (const float*)d_in[31];

  dim3 gD(32, 8);    // M-tiles(256) x N-tiles(128)
  dim3 gF1(32, 32);
  dim3 gVT(32, 2, 128);

  // ---- self-attention ----
  ln_fused<<<8192, 256, 0, stream>>>(x, ln1g, ln1b, x_pos, x2, qk);
  gemm_bt<0><<<gD, 512, 0, stream>>>(qk, Wt[0], (const float*)d_in[5], nullptr, Qb, 8192, 1024, 1024);
  gemm_bt<0><<<gD, 512, 0, stream>>>(qk, Wt[1], (const float*)d_in[7], nullptr, Kb, 8192, 1024, 1024);
  gemm_bt<0><<<gD, 512, 0, stream>>>(x2, Wt[2], (const float*)d_in[9], nullptr, Vb, 8192, 1024, 1024);
  vtrans<<<gVT, tb, 0, stream>>>(Vb, VTb);
  attn_fwd<<<1024, 256, 0, stream>>>(Qb, Kb, VTb, Ob);
  gemm_bt<1><<<gD, 512, 0, stream>>>(Ob, Wt[3], (const float*)d_in[11], x, xres, 8192, 1024, 1024);

  // ---- cross-attention ----
  ln_fused<<<8192, 256, 0, stream>>>(xres, ln2g, ln2b, x_pos, nullptr, qk);
  ln_fused<<<8192, 256, 0, stream>>>(y, ln3g, ln3b, y_pos, y2, yk);
  gemm_bt<0><<<gD, 512, 0, stream>>>(qk, Wt[4], (const float*)d_in[13], nullptr, Qb, 8192, 1024, 1024);
  gemm_bt<0><<<gD, 512, 0, stream>>>(yk, Wt[5], (const float*)d_in[15], nullptr, Kb, 8192, 1024, 1024);
  gemm_bt<0><<<gD, 512, 0, stream>>>(y2, Wt[6], (const float*)d_in[17], nullptr, Vb, 8192, 1024, 1024);
  vtrans<<<gVT, tb, 0, stream>>>(Vb, VTb);
  attn_fwd<<<1024, 256, 0, stream>>>(Qb, Kb, VTb, Ob);
  gemm_bt<1><<<gD, 512, 0, stream>>>(Ob, Wt[7], (const float*)d_in[19], xres, xres, 8192, 1024, 1024);

  // ---- FFN ----
  ln_fused<<<8192, 256, 0, stream>>>(xres, ln4g, ln4b, nullptr, x2, nullptr);
  gemm_bt<2><<<gF1, 512, 0, stream>>>(x2, W1T, (const float*)d_in[21], nullptr, hb, 8192, 4096, 1024);
  gemm_bt<1><<<gD, 512, 0, stream>>>(hb, W2T, (const float*)d_in[23], xres, (float*)d_out, 8192, 1024, 4096);
}